// Round 2
// baseline (2163.655 us; speedup 1.0000x reference)
//
#include <hip/hip_runtime.h>
#include <hip/hip_bf16.h>

#define N_NODES 10000
#define E_EDGES 160000
#define E2 (E_EDGES + N_NODES)
#define D_IN 256
#define H 128
#define HEADS 4
#define HD 512
#define L_LAYERS 16
#define OUT_DIM 1024
#define G_GRAPHS 8
#define EPS 1e-5f

typedef __hip_bfloat16 bf16;

__device__ __forceinline__ float tof(float v) { return v; }
__device__ __forceinline__ float tof(bf16 v) { return __bfloat162float(v); }

// ---------------- dtype probe ----------------
// flags[0] = 1 if float inputs are f32, 0 if bf16
// flags[1] = 1 if int inputs are int64, 0 if int32
__global__ void k_probe(const void* x, const void* ei, int* flags) {
    if (threadIdx.x != 0 || blockIdx.x != 0) return;
    const unsigned short* u = (const unsigned short*)x;
    int good = 0;
    for (int i = 0; i < 256; i++) {
        unsigned short w = u[2 * i];            // even 16-bit words
        int e = (w >> 7) & 0xFF;                // bf16 exponent field
        if (e >= 96 && e <= 150) good++;        // sane magnitude for N(0,1)
    }
    flags[0] = (good < 200) ? 1 : 0;            // f32 if even words look random
    const unsigned* e32 = (const unsigned*)ei;
    int allz = 1;
    for (int i = 0; i < 64; i++) if (e32[2 * i + 1] != 0) allz = 0;
    flags[1] = allz;                            // int64 if all high words zero
}

__device__ __forceinline__ int ldint(const void* p, size_t i, int i64) {
    return i64 ? ((const int*)p)[2 * i] : ((const int*)p)[i];
}

// ---------------- setup kernels ----------------

__global__ void k_zero(int* deg, int* cur, unsigned* g) {
    int i = blockIdx.x * blockDim.x + threadIdx.x;
    if (i < N_NODES) { deg[i] = 0; cur[i] = 0; }
    if (i < G_GRAPHS * H) g[i] = 0u;
}

__global__ void k_count(const void* ei, const int* flags, int* deg) {
    int i64 = flags[1];
    int e = blockIdx.x * blockDim.x + threadIdx.x;
    if (e >= E2) return;
    int d = (e < E_EDGES) ? ldint(ei, (size_t)E_EDGES + e, i64) : (e - E_EDGES);
    atomicAdd(&deg[d], 1);
}

__global__ void k_scan(const int* deg, int* rs) {
    __shared__ int s[1024];
    int t = threadIdx.x;
    int carry = 0;
    for (int base = 0; base < N_NODES; base += 1024) {
        int v = (base + t < N_NODES) ? deg[base + t] : 0;
        __syncthreads();
        s[t] = v;
        __syncthreads();
        for (int off = 1; off < 1024; off <<= 1) {
            int x = (t >= off) ? s[t - off] : 0;
            __syncthreads();
            s[t] += x;
            __syncthreads();
        }
        if (base + t < N_NODES) rs[base + t] = carry + s[t] - v;
        carry += s[1023];
    }
    if (t == 0) rs[N_NODES] = carry;
}

__global__ void k_fill(const void* ei, const int* flags, const int* rs, int* cur, int* elist) {
    int i64 = flags[1];
    int e = blockIdx.x * blockDim.x + threadIdx.x;
    if (e >= E2) return;
    int s, d;
    if (e < E_EDGES) {
        s = ldint(ei, (size_t)e, i64);
        d = ldint(ei, (size_t)E_EDGES + e, i64);
    } else { s = d = e - E_EDGES; }
    int pos = atomicAdd(&cur[d], 1);
    elist[rs[d] + pos] = s;
}

// v_src[l][head][j] = sum_k Wsrc[l][j][head*H+k] * att_src[l][head][k]
template<typename T>
__device__ void vw_body(const T* Wsrc, const T* Wdst, const T* As_, const T* Ad_,
                        float* vsrc, float* vdst) {
    int l = blockIdx.x;
    int t = threadIdx.x;           // 512
    int head = t >> 7, j = t & 127;
    const T* Ws = Wsrc + (size_t)l * H * HD;
    const T* Wd = Wdst + (size_t)l * H * HD;
    const T* As = As_ + (size_t)l * HEADS * H;
    const T* Ad = Ad_ + (size_t)l * HEADS * H;
    float ss = 0.f, sd = 0.f;
    for (int k = 0; k < H; k++) {
        ss += tof(Ws[(size_t)j * HD + head * H + k]) * tof(As[head * H + k]);
        sd += tof(Wd[(size_t)j * HD + head * H + k]) * tof(Ad[head * H + k]);
    }
    vsrc[(size_t)l * HD + head * H + j] = ss;
    vdst[(size_t)l * HD + head * H + j] = sd;
}
__global__ void k_vw(const void* Wsrc, const void* Wdst, const void* As, const void* Ad,
                     const int* flags, float* vsrc, float* vdst) {
    if (flags[0]) vw_body<float>((const float*)Wsrc, (const float*)Wdst,
                                 (const float*)As, (const float*)Ad, vsrc, vdst);
    else          vw_body<bf16>((const bf16*)Wsrc, (const bf16*)Wdst,
                                (const bf16*)As, (const bf16*)Ad, vsrc, vdst);
}

// ---------------- block reduce helper (blockDim.x == 128) ----------------
__device__ __forceinline__ void reduce2_b128(float& a, float& b, float* ls) {
    #pragma unroll
    for (int off = 32; off > 0; off >>= 1) {
        a += __shfl_down(a, off);
        b += __shfl_down(b, off);
    }
    int wid = threadIdx.x >> 6;
    __syncthreads();
    if ((threadIdx.x & 63) == 0) { ls[wid * 2] = a; ls[wid * 2 + 1] = b; }
    __syncthreads();
    a = ls[0] + ls[2];
    b = ls[1] + ls[3];
}

// ---------------- input layer: h = relu(LN(x@W_in + b_in)) ----------------
template<typename T>
__device__ void in_body(const T* x, const T* W_in, const T* b_in,
                        const T* lnw, const T* lnb, float* h) {
    __shared__ float xs[D_IN];
    __shared__ float ls[4];
    int row = blockIdx.x, c = threadIdx.x;
    xs[c]       = tof(x[(size_t)row * D_IN + c]);
    xs[c + 128] = tof(x[(size_t)row * D_IN + c + 128]);
    __syncthreads();
    float acc = 0.f;
    for (int k = 0; k < D_IN; k += 4) {
        float4 hv = *(const float4*)&xs[k];
        acc += hv.x * tof(W_in[(size_t)(k + 0) * H + c]);
        acc += hv.y * tof(W_in[(size_t)(k + 1) * H + c]);
        acc += hv.z * tof(W_in[(size_t)(k + 2) * H + c]);
        acc += hv.w * tof(W_in[(size_t)(k + 3) * H + c]);
    }
    acc += tof(b_in[c]);
    float s1 = acc, s2 = acc * acc;
    reduce2_b128(s1, s2, ls);
    float m = s1 * (1.f / 128.f);
    float var = s2 * (1.f / 128.f) - m * m;
    float y = (acc - m) * rsqrtf(var + EPS) * tof(lnw[c]) + tof(lnb[c]);
    h[(size_t)row * H + c] = fmaxf(y, 0.f);
}
__global__ void k_in(const void* x, const void* W_in, const void* b_in,
                     const void* lnw, const void* lnb, const int* flags, float* h) {
    if (flags[0]) in_body<float>((const float*)x, (const float*)W_in, (const float*)b_in,
                                 (const float*)lnw, (const float*)lnb, h);
    else          in_body<bf16>((const bf16*)x, (const bf16*)W_in, (const bf16*)b_in,
                                (const bf16*)lnw, (const bf16*)lnb, h);
}

// ---------------- S = h @ Wsrc[l] : 256 thr, 8 rows, 2 cols/thr; S stored bf16 ----------------
template<typename T>
__device__ void src_body(const float* h, const T* Wsrc, bf16* S, int l, float* smem) {
    float (*hs)[H] = (float(*)[H])smem;
    int t = threadIdx.x;
    int row0 = blockIdx.x * 8;
    for (int i = t; i < 8 * H; i += 256)
        hs[i >> 7][i & 127] = h[(size_t)(row0 + (i >> 7)) * H + (i & 127)];
    __syncthreads();
    const T* W = Wsrc + (size_t)l * H * HD;
    int c0 = t, c1 = t + 256;
    float acc[8][2];
    #pragma unroll
    for (int r = 0; r < 8; r++) { acc[r][0] = 0.f; acc[r][1] = 0.f; }
    for (int k = 0; k < H; k += 4) {
        float hreg[8][4];
        #pragma unroll
        for (int r = 0; r < 8; r++) {
            float4 v = *(const float4*)&hs[r][k];
            hreg[r][0] = v.x; hreg[r][1] = v.y; hreg[r][2] = v.z; hreg[r][3] = v.w;
        }
        #pragma unroll
        for (int kk = 0; kk < 4; kk++) {
            float wa = tof(W[(size_t)(k + kk) * HD + c0]);
            float wb = tof(W[(size_t)(k + kk) * HD + c1]);
            #pragma unroll
            for (int r = 0; r < 8; r++) {
                acc[r][0] += hreg[r][kk] * wa;
                acc[r][1] += hreg[r][kk] * wb;
            }
        }
    }
    #pragma unroll
    for (int r = 0; r < 8; r++) {
        S[(size_t)(row0 + r) * HD + c0] = __float2bfloat16(acc[r][0]);
        S[(size_t)(row0 + r) * HD + c1] = __float2bfloat16(acc[r][1]);
    }
}
__global__ void k_src(const float* __restrict__ h, const void* __restrict__ Wsrc,
                      const int* flags, bf16* __restrict__ S, int l) {
    extern __shared__ float smem[];
    if (flags[0]) src_body<float>(h, (const float*)Wsrc, S, l, smem);
    else          src_body<bf16>(h, (const bf16*)Wsrc, S, l, smem);
}

// ---------------- alphas: one wave per node ----------------
__global__ void k_alpha(const float* __restrict__ h, const float* __restrict__ vsrc,
                        const float* __restrict__ vdst,
                        float* __restrict__ as_, float* __restrict__ ad_, int l) {
    int wid = threadIdx.x >> 6, lane = threadIdx.x & 63;
    int n = blockIdx.x * 4 + wid;
    if (n >= N_NODES) return;
    float h0 = h[(size_t)n * H + lane];
    float h1 = h[(size_t)n * H + 64 + lane];
    const float* vs = vsrc + (size_t)l * HD;
    const float* vd = vdst + (size_t)l * HD;
    #pragma unroll
    for (int d = 0; d < HEADS; d++) {
        float p = h0 * vs[d * H + lane] + h1 * vs[d * H + 64 + lane];
        float q = h0 * vd[d * H + lane] + h1 * vd[d * H + 64 + lane];
        #pragma unroll
        for (int off = 32; off > 0; off >>= 1) {
            p += __shfl_down(p, off);
            q += __shfl_down(q, off);
        }
        if (lane == 0) { as_[n * HEADS + d] = p; ad_[n * HEADS + d] = q; }
    }
}

// ---------------- aggregation: block(512) per destination node ----------------
__global__ void k_agg(const bf16* __restrict__ S, const float* __restrict__ as_,
                      const float* __restrict__ ad_, const int* __restrict__ rs,
                      const int* __restrict__ elist, bf16* __restrict__ agg) {
    __shared__ int sl[128];
    __shared__ float wl[128][HEADS];
    int d = blockIdx.x, t = threadIdx.x;
    int start = rs[d], end = rs[d + 1];
    float4 adv = ((const float4*)ad_)[d];
    float acc0 = 0.f, acc1 = 0.f;
    int head = t >> 7;
    for (int chunk = start; chunk < end; chunk += 128) {
        int cnt = min(128, end - chunk);
        if (t < cnt) {
            int s = elist[chunk + t];
            sl[t] = s;
            float4 av = ((const float4*)as_)[s];
            float l0 = av.x + adv.x, l1 = av.y + adv.y, l2 = av.z + adv.z, l3 = av.w + adv.w;
            l0 = (l0 > 0.f) ? l0 : 0.2f * l0;
            l1 = (l1 > 0.f) ? l1 : 0.2f * l1;
            l2 = (l2 > 0.f) ? l2 : 0.2f * l2;
            l3 = (l3 > 0.f) ? l3 : 0.2f * l3;
            float m = fmaxf(fmaxf(l0, l1), fmaxf(l2, l3));
            float e0 = expf(l0 - m), e1 = expf(l1 - m), e2 = expf(l2 - m), e3 = expf(l3 - m);
            float inv = 1.f / (e0 + e1 + e2 + e3);
            wl[t][0] = e0 * inv; wl[t][1] = e1 * inv; wl[t][2] = e2 * inv; wl[t][3] = e3 * inv;
        }
        __syncthreads();
        int j = 0;
        for (; j + 1 < cnt; j += 2) {
            acc0 += wl[j][head]     * tof(S[(size_t)sl[j] * HD + t]);
            acc1 += wl[j + 1][head] * tof(S[(size_t)sl[j + 1] * HD + t]);
        }
        if (j < cnt) acc0 += wl[j][head] * tof(S[(size_t)sl[j] * HD + t]);
        __syncthreads();
    }
    agg[(size_t)d * HD + t] = __float2bfloat16(acc0 + acc1);
}

// ---------------- out GEMM + residual + LN + relu : block 128, 8 rows ----------------
template<typename T>
__device__ void out_body(const bf16* agg, const T* Wout, const T* bout,
                         const T* lnw, const T* lnb, float* h, int l, float* smem) {
    float (*as)[HD] = (float(*)[HD])smem;
    float* ls = smem + 8 * HD;
    int t = threadIdx.x;
    int row0 = blockIdx.x * 8;
    for (int i = t; i < 8 * HD; i += 128)
        as[i >> 9][i & 511] = tof(agg[(size_t)(row0 + (i >> 9)) * HD + (i & 511)]);
    __syncthreads();
    const T* W = Wout + (size_t)l * HD * H;
    float acc[8];
    #pragma unroll
    for (int r = 0; r < 8; r++) acc[r] = 0.f;
    for (int k = 0; k < HD; k += 4) {
        float hreg[8][4];
        #pragma unroll
        for (int r = 0; r < 8; r++) {
            float4 v = *(const float4*)&as[r][k];
            hreg[r][0] = v.x; hreg[r][1] = v.y; hreg[r][2] = v.z; hreg[r][3] = v.w;
        }
        #pragma unroll
        for (int kk = 0; kk < 4; kk++) {
            float wv = tof(W[(size_t)(k + kk) * H + t]);
            #pragma unroll
            for (int r = 0; r < 8; r++) acc[r] += hreg[r][kk] * wv;
        }
    }
    float bb = tof(bout[l * H + t]);
    float gw = tof(lnw[l * H + t]);
    float gb = tof(lnb[l * H + t]);
    for (int r = 0; r < 8; r++) {
        float v = acc[r] + bb + h[(size_t)(row0 + r) * H + t];
        float s1 = v, s2 = v * v;
        reduce2_b128(s1, s2, ls);
        float m = s1 * (1.f / 128.f);
        float var = s2 * (1.f / 128.f) - m * m;
        float y = (v - m) * rsqrtf(var + EPS) * gw + gb;
        h[(size_t)(row0 + r) * H + t] = fmaxf(y, 0.f);
    }
}
__global__ void k_out(const bf16* __restrict__ agg, const void* __restrict__ Wout,
                      const void* __restrict__ bout, const void* __restrict__ lnw,
                      const void* __restrict__ lnb, const int* flags,
                      float* __restrict__ h, int l) {
    extern __shared__ float smem[];
    if (flags[0]) out_body<float>(agg, (const float*)Wout, (const float*)bout,
                                  (const float*)lnw, (const float*)lnb, h, l, smem);
    else          out_body<bf16>(agg, (const bf16*)Wout, (const bf16*)bout,
                                 (const bf16*)lnw, (const bf16*)lnb, h, l, smem);
}

// ---------------- pooling + MLPs ----------------
__global__ void k_pool(const float* __restrict__ h, const void* __restrict__ batch,
                       const int* flags, unsigned* __restrict__ g) {
    __shared__ float lm[G_GRAPHS][H];
    int i64 = flags[1];
    int t = threadIdx.x;
    #pragma unroll
    for (int i = 0; i < G_GRAPHS; i++) lm[i][t] = 0.f;
    int n0 = blockIdx.x * 250, n1 = n0 + 250;
    for (int n = n0; n < n1; n++) {
        int b = ldint(batch, (size_t)n, i64);
        lm[b][t] = fmaxf(lm[b][t], h[(size_t)n * H + t]);
    }
    #pragma unroll
    for (int i = 0; i < G_GRAPHS; i++)
        atomicMax(&g[i * H + t], __float_as_uint(lm[i][t]));
}

template<typename T>
__device__ void mlp1_body(const unsigned* g, const T* Wp1, const T* bp1, float* g1) {
    __shared__ float gs[H];
    int row = blockIdx.x, t = threadIdx.x;
    if (t < H) gs[t] = __uint_as_float(g[row * H + t]);
    __syncthreads();
    float acc = 0.f;
    for (int k = 0; k < H; k++) acc += gs[k] * tof(Wp1[(size_t)k * OUT_DIM + t]);
    acc += tof(bp1[t]);
    g1[(size_t)row * OUT_DIM + t] = fmaxf(acc, 0.f);
}
__global__ void k_mlp1(const unsigned* g, const void* Wp1, const void* bp1,
                       const int* flags, float* g1) {
    if (flags[0]) mlp1_body<float>(g, (const float*)Wp1, (const float*)bp1, g1);
    else          mlp1_body<bf16>(g, (const bf16*)Wp1, (const bf16*)bp1, g1);
}

template<typename T>
__device__ void mlp2_body(const float* g1, const T* Wp2, const T* bp2, void* out, int f32out) {
    __shared__ float gs[OUT_DIM];
    int row = blockIdx.x, t = threadIdx.x;
    gs[t] = g1[(size_t)row * OUT_DIM + t];
    __syncthreads();
    float acc = 0.f;
    for (int k = 0; k < OUT_DIM; k++) acc += gs[k] * tof(Wp2[(size_t)k * OUT_DIM + t]);
    acc += tof(bp2[t]);
    if (f32out) ((float*)out)[(size_t)row * OUT_DIM + t] = acc;
    else        ((bf16*)out)[(size_t)row * OUT_DIM + t] = __float2bfloat16(acc);
}
__global__ void k_mlp2(const float* g1, const void* Wp2, const void* bp2,
                       const int* flags, void* out) {
    if (flags[0]) mlp2_body<float>(g1, (const float*)Wp2, (const float*)bp2, out, 1);
    else          mlp2_body<bf16>(g1, (const bf16*)Wp2, (const bf16*)bp2, out, 0);
}

// ---------------- launch ----------------
extern "C" void kernel_launch(void* const* d_in, const int* in_sizes, int n_in,
                              void* d_out, int out_size, void* d_ws, size_t ws_size,
                              hipStream_t stream) {
    const void* x       = d_in[0];
    const void* ei      = d_in[1];
    const void* batch   = d_in[2];
    const void* W_in    = d_in[3];
    const void* b_in    = d_in[4];
    const void* ln_in_w = d_in[5];
    const void* ln_in_b = d_in[6];
    const void* Wsrc    = d_in[7];
    const void* Wdst    = d_in[8];
    const void* att_src = d_in[9];
    const void* att_dst = d_in[10];
    const void* Wout    = d_in[11];
    const void* bout    = d_in[12];
    const void* ln_w    = d_in[13];
    const void* ln_b    = d_in[14];
    const void* Wp1     = d_in[15];
    const void* bp1     = d_in[16];
    const void* Wp2     = d_in[17];
    const void* bp2     = d_in[18];

    char* w = (char*)d_ws;
    auto alloc = [&](size_t bytes) { void* p = w; w += (bytes + 255) & ~(size_t)255; return p; };
    float*    h     = (float*)alloc((size_t)N_NODES * H * 4);
    bf16*     S     = (bf16*)alloc((size_t)N_NODES * HD * 2);
    bf16*     agg   = (bf16*)alloc((size_t)N_NODES * HD * 2);
    float*    as_   = (float*)alloc((size_t)N_NODES * HEADS * 4);
    float*    ad_   = (float*)alloc((size_t)N_NODES * HEADS * 4);
    float*    vsrc  = (float*)alloc((size_t)L_LAYERS * HD * 4);
    float*    vdst  = (float*)alloc((size_t)L_LAYERS * HD * 4);
    int*      deg   = (int*)alloc((size_t)N_NODES * 4);
    int*      rs    = (int*)alloc((size_t)(N_NODES + 1) * 4);
    int*      cur   = (int*)alloc((size_t)N_NODES * 4);
    int*      elist = (int*)alloc((size_t)E2 * 4);
    unsigned* g     = (unsigned*)alloc((size_t)G_GRAPHS * H * 4);
    float*    g1    = (float*)alloc((size_t)G_GRAPHS * OUT_DIM * 4);
    int*      flags = (int*)alloc(64);

    k_probe<<<1, 64, 0, stream>>>(x, ei, flags);
    k_zero<<<40, 256, 0, stream>>>(deg, cur, g);
    k_count<<<(E2 + 255) / 256, 256, 0, stream>>>(ei, flags, deg);
    k_scan<<<1, 1024, 0, stream>>>(deg, rs);
    k_fill<<<(E2 + 255) / 256, 256, 0, stream>>>(ei, flags, rs, cur, elist);
    k_vw<<<L_LAYERS, 512, 0, stream>>>(Wsrc, Wdst, att_src, att_dst, flags, vsrc, vdst);
    k_in<<<N_NODES, 128, 0, stream>>>(x, W_in, b_in, ln_in_w, ln_in_b, flags, h);

    for (int l = 0; l < L_LAYERS; l++) {
        k_src<<<N_NODES / 8, 256, 8 * H * 4, stream>>>(h, Wsrc, flags, S, l);
        k_alpha<<<N_NODES / 4, 256, 0, stream>>>(h, vsrc, vdst, as_, ad_, l);
        k_agg<<<N_NODES, 512, 0, stream>>>(S, as_, ad_, rs, elist, agg);
        k_out<<<N_NODES / 8, 128, (8 * HD + 4) * 4, stream>>>(agg, Wout, bout, ln_w, ln_b, flags, h, l);
    }

    k_pool<<<40, 128, 0, stream>>>(h, batch, flags, g);
    k_mlp1<<<G_GRAPHS, 1024, 0, stream>>>(g, Wp1, bp1, flags, g1);
    k_mlp2<<<G_GRAPHS, 1024, 0, stream>>>(g1, Wp2, bp2, flags, (void*)d_out);
}

// Round 4
// 861.503 us; speedup vs baseline: 2.5115x; 2.5115x over previous
//
#include <hip/hip_runtime.h>
#include <hip/hip_bf16.h>

#define N_NODES 10000
#define E_EDGES 160000
#define E2 (E_EDGES + N_NODES)
#define D_IN 256
#define H 128
#define HEADS 4
#define HD 512
#define L_LAYERS 16
#define OUT_DIM 1024
#define G_GRAPHS 8
#define EPS 1e-5f
#define HBPAD 10016   // hb rows padded: k_src last block reads rows up to 10015

typedef unsigned short ushort_t;
typedef __attribute__((ext_vector_type(8))) short short8;
typedef __attribute__((ext_vector_type(4))) float f32x4;
typedef __attribute__((ext_vector_type(4))) unsigned u32x4;

__device__ __forceinline__ f32x4 mfma16(short8 a, short8 b, f32x4 c) {
    return __builtin_amdgcn_mfma_f32_16x16x32_bf16(a, b, c, 0, 0, 0);
}
__device__ __forceinline__ unsigned short f2b(float f) {   // f32 -> bf16 bits, RNE
    unsigned u = __float_as_uint(f);
    u += 0x7fffu + ((u >> 16) & 1u);
    return (unsigned short)(u >> 16);
}

// ---------------- setup: CSR build (edges are int32!) ----------------
__global__ void k_zero(int* deg, int* cur, unsigned* g) {
    int i = blockIdx.x * blockDim.x + threadIdx.x;
    if (i < N_NODES) { deg[i] = 0; cur[i] = 0; }
    if (i < G_GRAPHS * H) g[i] = 0u;
}

__global__ void k_count(const int* ei, int* deg) {
    int e = blockIdx.x * blockDim.x + threadIdx.x;
    if (e >= E2) return;
    int d = (e < E_EDGES) ? ei[E_EDGES + e] : (e - E_EDGES);
    atomicAdd(&deg[d], 1);
}

__global__ void k_scan(const int* deg, int* rs) {
    __shared__ int s[1024];
    int t = threadIdx.x;
    int carry = 0;
    for (int base = 0; base < N_NODES; base += 1024) {
        int v = (base + t < N_NODES) ? deg[base + t] : 0;
        __syncthreads();
        s[t] = v;
        __syncthreads();
        for (int off = 1; off < 1024; off <<= 1) {
            int x = (t >= off) ? s[t - off] : 0;
            __syncthreads();
            s[t] += x;
            __syncthreads();
        }
        if (base + t < N_NODES) rs[base + t] = carry + s[t] - v;
        carry += s[1023];
    }
    if (t == 0) rs[N_NODES] = carry;
}

__global__ void k_fill(const int* ei, const int* rs, int* cur, int* elist) {
    int e = blockIdx.x * blockDim.x + threadIdx.x;
    if (e >= E2) return;
    int s, d;
    if (e < E_EDGES) { s = ei[e]; d = ei[E_EDGES + e]; }
    else { s = d = e - E_EDGES; }
    int pos = atomicAdd(&cur[d], 1);
    elist[rs[d] + pos] = s;
}

// ---------------- weight preprocessing ----------------
__global__ void k_vw(const float* Wsrc, const float* Wdst,
                     const float* att_src, const float* att_dst,
                     float* vsrc, float* vdst) {
    int l = blockIdx.x;
    int t = threadIdx.x;           // 512
    int head = t >> 7, j = t & 127;
    const float* Ws = Wsrc + (size_t)l * H * HD;
    const float* Wd = Wdst + (size_t)l * H * HD;
    const float* As = att_src + (size_t)l * HEADS * H;
    const float* Ad = att_dst + (size_t)l * HEADS * H;
    float ss = 0.f, sd = 0.f;
    for (int k = 0; k < H; k++) {
        ss += Ws[(size_t)j * HD + head * H + k] * As[head * H + k];
        sd += Wd[(size_t)j * HD + head * H + k] * Ad[head * H + k];
    }
    vsrc[(size_t)l * HD + head * H + j] = ss;
    vdst[(size_t)l * HD + head * H + j] = sd;
}

// pack Wsrc [L][128k][512col] f32 -> B-frag layout [L][nt32][ks4][lane64][j8] bf16
__global__ void k_pack_src(const float* W, ushort_t* Wp) {
    int idx = blockIdx.x * 256 + threadIdx.x;           // 16*65536 total
    int l = idx >> 16, rem = idx & 65535;
    int k = rem >> 9, col = rem & 511;
    float v = W[(size_t)l * H * HD + (size_t)k * HD + col];
    int nt = col >> 4, ks = k >> 5, lhi = (k >> 3) & 3, llo = col & 15, j = k & 7;
    Wp[(size_t)l * 65536 + (((size_t)(nt * 4 + ks) * 64) + lhi * 16 + llo) * 8 + j] = f2b(v);
}

// pack Wout [L][512k][128col] f32 -> [L][nt8][ks16][lane64][j8] bf16
__global__ void k_pack_out(const float* W, ushort_t* Wp) {
    int idx = blockIdx.x * 256 + threadIdx.x;           // 16*65536 total
    int l = idx >> 16, rem = idx & 65535;
    int k = rem >> 7, col = rem & 127;
    float v = W[(size_t)l * HD * H + (size_t)k * H + col];
    int nt = col >> 4, ks = k >> 5, lhi = (k >> 3) & 3, llo = col & 15, j = k & 7;
    Wp[(size_t)l * 65536 + (((size_t)(nt * 16 + ks) * 64) + lhi * 16 + llo) * 8 + j] = f2b(v);
}

// pack alpha tile: B[k][col]: col<4 -> vsrc[head=col], col in 4..7 -> vdst, else 0
__global__ void k_pack_alpha(const float* vsrc, const float* vdst, ushort_t* Ap) {
    int idx = blockIdx.x * 256 + threadIdx.x;           // 16*2048 total
    int l = idx >> 11, r = idx & 2047;
    int ks = r >> 9, lane = (r >> 3) & 63, j = r & 7;
    int col = lane & 15;
    int k = ks * 32 + (lane >> 4) * 8 + j;
    float v = 0.f;
    if (col < 4)      v = vsrc[(size_t)l * HD + col * H + k];
    else if (col < 8) v = vdst[(size_t)l * HD + (col - 4) * H + k];
    Ap[idx] = f2b(v);
}

// ---------------- input layer: 16 rows/block ----------------
__global__ __launch_bounds__(128) void k_in(
        const float* __restrict__ x, const float* __restrict__ W_in,
        const float* __restrict__ b_in, const float* __restrict__ lnw,
        const float* __restrict__ lnb, float* __restrict__ h, ushort_t* __restrict__ hb) {
    __shared__ float xs[16][D_IN];
    __shared__ float ls[4];
    int t = threadIdx.x;
    int row0 = blockIdx.x * 16;
    for (int i = t; i < 16 * D_IN; i += 128)
        xs[i >> 8][i & 255] = x[(size_t)(row0 + (i >> 8)) * D_IN + (i & 255)];
    __syncthreads();
    float acc[16];
    #pragma unroll
    for (int r = 0; r < 16; r++) acc[r] = 0.f;
    int c = t;
    for (int k = 0; k < D_IN; k += 4) {
        float w0 = W_in[(size_t)(k + 0) * H + c];
        float w1 = W_in[(size_t)(k + 1) * H + c];
        float w2 = W_in[(size_t)(k + 2) * H + c];
        float w3 = W_in[(size_t)(k + 3) * H + c];
        #pragma unroll
        for (int r = 0; r < 16; r++) {
            float4 xv = *(const float4*)&xs[r][k];
            acc[r] += xv.x * w0 + xv.y * w1 + xv.z * w2 + xv.w * w3;
        }
    }
    float bb = b_in[c], gw = lnw[c], gb = lnb[c];
    for (int r = 0; r < 16; r++) {
        float v = acc[r] + bb;
        float s1 = v, s2 = v * v;
        #pragma unroll
        for (int off = 32; off > 0; off >>= 1) {
            s1 += __shfl_down(s1, off);
            s2 += __shfl_down(s2, off);
        }
        int wid = t >> 6;
        __syncthreads();
        if ((t & 63) == 0) { ls[wid * 2] = s1; ls[wid * 2 + 1] = s2; }
        __syncthreads();
        s1 = ls[0] + ls[2];
        s2 = ls[1] + ls[3];
        float m = s1 * (1.f / 128.f);
        float var = s2 * (1.f / 128.f) - m * m;
        float y = (v - m) * rsqrtf(var + EPS) * gw + gb;
        y = fmaxf(y, 0.f);
        int row = row0 + r;
        h[(size_t)row * H + c] = y;
        hb[(size_t)row * H + c] = f2b(y);
    }
}

// ---------------- S = hb @ Wsrc (MFMA) + fused alpha ----------------
// block 256 = 4 waves; 32 rows; wave w owns cols [w*128, w*128+128)
__global__ __launch_bounds__(256) void k_src_mfma(
        const ushort_t* __restrict__ hb, const ushort_t* __restrict__ Wp,
        const ushort_t* __restrict__ Ap, ushort_t* __restrict__ S,
        float* __restrict__ as_, float* __restrict__ ad_, int l) {
    int t = threadIdx.x, w = t >> 6, lane = t & 63;
    int row0 = blockIdx.x * 32;
    const ushort_t* WL = Wp + (size_t)l * 65536;
    int ar = lane & 15, ac = (lane >> 4) * 8;
    short8 a[2][4];
    #pragma unroll
    for (int mt = 0; mt < 2; mt++)
        #pragma unroll
        for (int ks = 0; ks < 4; ks++)
            a[mt][ks] = *(const short8*)(hb + (size_t)(row0 + mt * 16 + ar) * H + ks * 32 + ac);
    int rb = row0 + (lane >> 4) * 4;
    #pragma unroll
    for (int nt = 0; nt < 8; nt++) {
        int ntg = w * 8 + nt;
        f32x4 c0 = {0.f, 0.f, 0.f, 0.f}, c1 = {0.f, 0.f, 0.f, 0.f};
        #pragma unroll
        for (int ks = 0; ks < 4; ks++) {
            short8 b = *(const short8*)(WL + ((size_t)(ntg * 4 + ks) * 64 + lane) * 8);
            c0 = mfma16(a[0][ks], b, c0);
            c1 = mfma16(a[1][ks], b, c1);
        }
        int col = ntg * 16 + ar;
        #pragma unroll
        for (int r = 0; r < 4; r++) {
            int r0 = rb + r;
            if (r0 < N_NODES) S[(size_t)r0 * HD + col] = f2b(c0[r]);
            int r1 = rb + 16 + r;
            if (r1 < N_NODES) S[(size_t)r1 * HD + col] = f2b(c1[r]);
        }
    }
    if (w == 0) {   // fused alpha: one extra 16-col B tile (cols 0-3=asrc, 4-7=adst)
        const ushort_t* AL = Ap + (size_t)l * 2048;
        f32x4 c0 = {0.f, 0.f, 0.f, 0.f}, c1 = {0.f, 0.f, 0.f, 0.f};
        #pragma unroll
        for (int ks = 0; ks < 4; ks++) {
            short8 b = *(const short8*)(AL + ((size_t)ks * 64 + lane) * 8);
            c0 = mfma16(a[0][ks], b, c0);
            c1 = mfma16(a[1][ks], b, c1);
        }
        if (ar < 8) {
            float* dst = (ar < 4) ? as_ : ad_;
            int cc = ar & 3;
            #pragma unroll
            for (int r = 0; r < 4; r++) {
                int r0 = rb + r;
                if (r0 < N_NODES) dst[r0 * 4 + cc] = c0[r];
                int r1 = rb + 16 + r;
                if (r1 < N_NODES) dst[r1 * 4 + cc] = c1[r];
            }
        }
    }
}

// ---------------- fused aggregation + out-GEMM + residual + LN + relu ----------------
// block 256 = 4 waves, 16 nodes. Wave w aggregates nodes base+4w..base+4w+3 into a
// swizzled LDS A-tile, then all waves do the 16x128 GEMM (K=512) + LN epilogue.
__global__ __launch_bounds__(256) void k_aggout(
        const ushort_t* __restrict__ S, const float4* __restrict__ as4,
        const float4* __restrict__ ad4, const int* __restrict__ rs,
        const int* __restrict__ elist, const ushort_t* __restrict__ Wp,
        const float* __restrict__ bout, const float* __restrict__ lnw,
        const float* __restrict__ lnb, float* __restrict__ h,
        ushort_t* __restrict__ hb, int l) {
    __shared__ ushort_t frag[16 * 64 * 8];      // 16KB, 16B granule (l,ks) at l*16+(ks^(l&15))
    __shared__ int sl[4][64];
    __shared__ float wl[4][64][4];
    __shared__ float part1[4][16], part2[4][16];
    int t = threadIdx.x, w = t >> 6, lane = t & 63;
    int base = blockIdx.x * 16;
    int head = lane >> 4;

    // ---- phase 1: aggregate 4 nodes per wave ----
    for (int q = 0; q < 4; q++) {
        int r = w * 4 + q;
        int node = base + r;
        int start = rs[node], end = rs[node + 1];
        float4 adv = ad4[node];
        float acc[8];
        #pragma unroll
        for (int i = 0; i < 8; i++) acc[i] = 0.f;
        for (int c0 = start; c0 < end; c0 += 64) {
            int cnt = min(64, end - c0);
            if (lane < cnt) {
                int s = elist[c0 + lane];
                sl[w][lane] = s;
                float4 av = as4[s];
                float l0 = av.x + adv.x, l1 = av.y + adv.y, l2 = av.z + adv.z, l3 = av.w + adv.w;
                l0 = (l0 > 0.f) ? l0 : 0.2f * l0;
                l1 = (l1 > 0.f) ? l1 : 0.2f * l1;
                l2 = (l2 > 0.f) ? l2 : 0.2f * l2;
                l3 = (l3 > 0.f) ? l3 : 0.2f * l3;
                float mx = fmaxf(fmaxf(l0, l1), fmaxf(l2, l3));
                float e0 = expf(l0 - mx), e1 = expf(l1 - mx), e2 = expf(l2 - mx), e3 = expf(l3 - mx);
                float inv = 1.f / (e0 + e1 + e2 + e3);
                wl[w][lane][0] = e0 * inv;
                wl[w][lane][1] = e1 * inv;
                wl[w][lane][2] = e2 * inv;
                wl[w][lane][3] = e3 * inv;
            }
            __asm__ volatile("s_waitcnt lgkmcnt(0)" ::: "memory");
            for (int j = 0; j < cnt; j++) {
                int s = sl[w][j];
                float wt = wl[w][j][head];
                u32x4 uv = *(const u32x4*)(S + (size_t)s * HD + lane * 8);
                acc[0] += wt * __uint_as_float(uv.x << 16);
                acc[1] += wt * __uint_as_float(uv.x & 0xffff0000u);
                acc[2] += wt * __uint_as_float(uv.y << 16);
                acc[3] += wt * __uint_as_float(uv.y & 0xffff0000u);
                acc[4] += wt * __uint_as_float(uv.z << 16);
                acc[5] += wt * __uint_as_float(uv.z & 0xffff0000u);
                acc[6] += wt * __uint_as_float(uv.w << 16);
                acc[7] += wt * __uint_as_float(uv.w & 0xffff0000u);
            }
        }
        // lane holds cols [8*lane, 8*lane+8) of node row r -> A-frag granule
        // consumer (l = (lane&3)*16 + r, ks = lane>>2); swizzled byte offset
        u32x4 o;
        o.x = (unsigned)f2b(acc[0]) | ((unsigned)f2b(acc[1]) << 16);
        o.y = (unsigned)f2b(acc[2]) | ((unsigned)f2b(acc[3]) << 16);
        o.z = (unsigned)f2b(acc[4]) | ((unsigned)f2b(acc[5]) << 16);
        o.w = (unsigned)f2b(acc[6]) | ((unsigned)f2b(acc[7]) << 16);
        int gidx = ((lane & 3) * 16 + r) * 16 + ((lane >> 2) ^ r);
        *(u32x4*)((char*)frag + gidx * 16) = o;
    }
    __syncthreads();

    // ---- phase 2: out-GEMM 16x128, K=512 ----
    const ushort_t* WL = Wp + (size_t)l * 65536;
    short8 a[16];
    #pragma unroll
    for (int ks = 0; ks < 16; ks++) {
        int gidx = lane * 16 + (ks ^ (lane & 15));
        a[ks] = *(const short8*)((const char*)frag + gidx * 16);
    }
    int ar = lane & 15;
    f32x4 c0 = {0.f, 0.f, 0.f, 0.f}, c1 = {0.f, 0.f, 0.f, 0.f};
    #pragma unroll
    for (int ks = 0; ks < 16; ks++) {
        short8 b0 = *(const short8*)(WL + ((size_t)((w * 2 + 0) * 16 + ks) * 64 + lane) * 8);
        short8 b1 = *(const short8*)(WL + ((size_t)((w * 2 + 1) * 16 + ks) * 64 + lane) * 8);
        c0 = mfma16(a[ks], b0, c0);
        c1 = mfma16(a[ks], b1, c1);
    }

    // ---- phase 3: bias + residual + LN + relu ----
    const float* bo = bout + (size_t)l * H;
    const float* gw = lnw + (size_t)l * H;
    const float* gb = lnb + (size_t)l * H;
    int col0 = (w * 2 + 0) * 16 + ar;
    int col1 = (w * 2 + 1) * 16 + ar;
    int rb = (lane >> 4) * 4;
    float v0[4], v1[4];
    #pragma unroll
    for (int r = 0; r < 4; r++) {
        int row = base + rb + r;
        v0[r] = c0[r] + bo[col0] + h[(size_t)row * H + col0];
        v1[r] = c1[r] + bo[col1] + h[(size_t)row * H + col1];
        float p1 = v0[r] + v1[r];
        float p2 = v0[r] * v0[r] + v1[r] * v1[r];
        #pragma unroll
        for (int off = 1; off < 16; off <<= 1) {
            p1 += __shfl_xor(p1, off);
            p2 += __shfl_xor(p2, off);
        }
        if (ar == 0) { part1[w][rb + r] = p1; part2[w][rb + r] = p2; }
    }
    __syncthreads();
    #pragma unroll
    for (int r = 0; r < 4; r++) {
        int lr = rb + r;
        int row = base + lr;
        float s1 = part1[0][lr] + part1[1][lr] + part1[2][lr] + part1[3][lr];
        float s2 = part2[0][lr] + part2[1][lr] + part2[2][lr] + part2[3][lr];
        float m = s1 * (1.f / 128.f);
        float var = s2 * (1.f / 128.f) - m * m;
        float is = rsqrtf(var + EPS);
        float y0 = fmaxf((v0[r] - m) * is * gw[col0] + gb[col0], 0.f);
        float y1 = fmaxf((v1[r] - m) * is * gw[col1] + gb[col1], 0.f);
        h[(size_t)row * H + col0] = y0;
        h[(size_t)row * H + col1] = y1;
        hb[(size_t)row * H + col0] = f2b(y0);
        hb[(size_t)row * H + col1] = f2b(y1);
    }
}

// ---------------- pooling + MLPs ----------------
__global__ void k_pool(const float* __restrict__ h, const int* __restrict__ batch,
                       unsigned* __restrict__ g) {
    __shared__ float lm[G_GRAPHS][H];
    int t = threadIdx.x;
    #pragma unroll
    for (int i = 0; i < G_GRAPHS; i++) lm[i][t] = 0.f;
    int n0 = blockIdx.x * 250, n1 = n0 + 250;
    for (int n = n0; n < n1; n++) {
        int b = batch[n];
        lm[b][t] = fmaxf(lm[b][t], h[(size_t)n * H + t]);
    }
    #pragma unroll
    for (int i = 0; i < G_GRAPHS; i++)
        atomicMax(&g[i * H + t], __float_as_uint(lm[i][t]));
}

__global__ void k_mlp1(const unsigned* __restrict__ g, const float* __restrict__ Wp1,
                       const float* __restrict__ bp1, float* __restrict__ g1) {
    __shared__ float gs[H];
    int gr = blockIdx.x >> 2, ch = blockIdx.x & 3;
    int t = threadIdx.x;                        // 256
    if (t < H) gs[t] = __uint_as_float(g[gr * H + t]);
    __syncthreads();
    int col = ch * 256 + t;
    float acc = 0.f;
    for (int k = 0; k < H; k++) acc += gs[k] * Wp1[(size_t)k * OUT_DIM + col];
    acc += bp1[col];
    g1[(size_t)gr * OUT_DIM + col] = fmaxf(acc, 0.f);
}

__global__ void k_mlp2(const float* __restrict__ g1, const float* __restrict__ Wp2,
                       const float* __restrict__ bp2, float* __restrict__ out) {
    __shared__ float gs[OUT_DIM];
    __shared__ float part[4][64];
    int gr = blockIdx.x >> 4, ch = blockIdx.x & 15;
    int t = threadIdx.x;                        // 256
    int ci = t & 63, si = t >> 6;
    for (int i = t; i < OUT_DIM; i += 256) gs[i] = g1[(size_t)gr * OUT_DIM + i];
    __syncthreads();
    int col = ch * 64 + ci;
    float acc = 0.f;
    for (int k = si * 256; k < si * 256 + 256; k++)
        acc += gs[k] * Wp2[(size_t)k * OUT_DIM + col];
    part[si][ci] = acc;
    __syncthreads();
    if (si == 0) {
        float r = part[0][ci] + part[1][ci] + part[2][ci] + part[3][ci] + bp2[col];
        out[(size_t)gr * OUT_DIM + col] = r;
    }
}

// ---------------- launch ----------------
extern "C" void kernel_launch(void* const* d_in, const int* in_sizes, int n_in,
                              void* d_out, int out_size, void* d_ws, size_t ws_size,
                              hipStream_t stream) {
    const float* x       = (const float*)d_in[0];
    const int*   ei      = (const int*)d_in[1];     // int32
    const int*   batch   = (const int*)d_in[2];     // int32
    const float* W_in    = (const float*)d_in[3];
    const float* b_in    = (const float*)d_in[4];
    const float* ln_in_w = (const float*)d_in[5];
    const float* ln_in_b = (const float*)d_in[6];
    const float* Wsrc    = (const float*)d_in[7];
    const float* Wdst    = (const float*)d_in[8];
    const float* att_src = (const float*)d_in[9];
    const float* att_dst = (const float*)d_in[10];
    const float* Wout    = (const float*)d_in[11];
    const float* bout    = (const float*)d_in[12];
    const float* ln_w    = (const float*)d_in[13];
    const float* ln_b    = (const float*)d_in[14];
    const float* Wp1     = (const float*)d_in[15];
    const float* bp1     = (const float*)d_in[16];
    const float* Wp2     = (const float*)d_in[17];
    const float* bp2     = (const float*)d_in[18];

    char* w = (char*)d_ws;
    auto alloc = [&](size_t bytes) { void* p = w; w += (bytes + 255) & ~(size_t)255; return p; };
    float*     h     = (float*)alloc((size_t)N_NODES * H * 4);
    ushort_t*  hb    = (ushort_t*)alloc((size_t)HBPAD * H * 2);
    ushort_t*  S     = (ushort_t*)alloc((size_t)N_NODES * HD * 2);
    float*     as_   = (float*)alloc((size_t)N_NODES * HEADS * 4);
    float*     ad_   = (float*)alloc((size_t)N_NODES * HEADS * 4);
    float*     vsrc  = (float*)alloc((size_t)L_LAYERS * HD * 4);
    float*     vdst  = (float*)alloc((size_t)L_LAYERS * HD * 4);
    ushort_t*  WpS   = (ushort_t*)alloc((size_t)L_LAYERS * 65536 * 2);
    ushort_t*  WpO   = (ushort_t*)alloc((size_t)L_LAYERS * 65536 * 2);
    ushort_t*  Ap    = (ushort_t*)alloc((size_t)L_LAYERS * 2048 * 2);
    int*       deg   = (int*)alloc((size_t)N_NODES * 4);
    int*       rs    = (int*)alloc((size_t)(N_NODES + 1) * 4);
    int*       cur   = (int*)alloc((size_t)N_NODES * 4);
    int*       elist = (int*)alloc((size_t)E2 * 4);
    unsigned*  g     = (unsigned*)alloc((size_t)G_GRAPHS * H * 4);
    float*     g1    = (float*)alloc((size_t)G_GRAPHS * OUT_DIM * 4);

    k_zero<<<40, 256, 0, stream>>>(deg, cur, g);
    k_count<<<(E2 + 255) / 256, 256, 0, stream>>>(ei, deg);
    k_scan<<<1, 1024, 0, stream>>>(deg, rs);
    k_fill<<<(E2 + 255) / 256, 256, 0, stream>>>(ei, rs, cur, elist);
    k_vw<<<L_LAYERS, 512, 0, stream>>>(Wsrc, Wdst, att_src, att_dst, vsrc, vdst);
    k_pack_src<<<4096, 256, 0, stream>>>(Wsrc, WpS);
    k_pack_out<<<4096, 256, 0, stream>>>(Wout, WpO);
    k_pack_alpha<<<128, 256, 0, stream>>>(vsrc, vdst, Ap);
    k_in<<<N_NODES / 16, 128, 0, stream>>>(x, W_in, b_in, ln_in_w, ln_in_b, h, hb);

    for (int l = 0; l < L_LAYERS; l++) {
        k_src_mfma<<<313, 256, 0, stream>>>(hb, WpS, Ap, S, as_, ad_, l);
        k_aggout<<<N_NODES / 16, 256, 0, stream>>>(S, (const float4*)as_, (const float4*)ad_,
                                                   rs, elist, WpO, bout, ln_w, ln_b, h, hb, l);
    }

    k_pool<<<40, 128, 0, stream>>>(h, batch, g);
    k_mlp1<<<G_GRAPHS * 4, 256, 0, stream>>>(g, Wp1, bp1, g1);
    k_mlp2<<<G_GRAPHS * 16, 256, 0, stream>>>(g1, Wp2, bp2, (float*)d_out);
}

// Round 5
// 796.229 us; speedup vs baseline: 2.7174x; 1.0820x over previous
//
#include <hip/hip_runtime.h>
#include <hip/hip_bf16.h>

#define N_NODES 10000
#define E_EDGES 160000
#define E2 (E_EDGES + N_NODES)
#define D_IN 256
#define H 128
#define HEADS 4
#define HD 512
#define L_LAYERS 16
#define OUT_DIM 1024
#define G_GRAPHS 8
#define EPS 1e-5f
#define SPAD 10016   // padded rows for S / as_ / ad_ / hb (k_src tiles run to 10015)

typedef unsigned short ushort_t;
typedef __attribute__((ext_vector_type(8))) short short8;
typedef __attribute__((ext_vector_type(4))) float f32x4;
typedef __attribute__((ext_vector_type(4))) unsigned u32x4;

__device__ __forceinline__ f32x4 mfma16(short8 a, short8 b, f32x4 c) {
    return __builtin_amdgcn_mfma_f32_16x16x32_bf16(a, b, c, 0, 0, 0);
}
__device__ __forceinline__ unsigned short f2b(float f) {   // f32 -> bf16 bits, RNE
    unsigned u = __float_as_uint(f);
    u += 0x7fffu + ((u >> 16) & 1u);
    return (unsigned short)(u >> 16);
}
__device__ __forceinline__ unsigned pk2(float lo, float hi) {  // 2xf32 -> packed bf16x2
    __hip_bfloat162 p = __float22bfloat162_rn(make_float2(lo, hi));
    return *(unsigned*)&p;
}

// ---------------- setup: CSR build (int32 edges) ----------------
__global__ void k_zero(int* deg, int* cur, unsigned* g) {
    int i = blockIdx.x * blockDim.x + threadIdx.x;
    if (i < N_NODES) { deg[i] = 0; cur[i] = 0; }
    if (i < G_GRAPHS * H) g[i] = 0u;
}

__global__ void k_count(const int* ei, int* deg) {
    int e = blockIdx.x * blockDim.x + threadIdx.x;
    if (e >= E2) return;
    int d = (e < E_EDGES) ? ei[E_EDGES + e] : (e - E_EDGES);
    atomicAdd(&deg[d], 1);
}

__global__ void k_scan(const int* deg, int* rs) {   // 1 block x 1024, 10 elems/thread
    __shared__ int s[1024];
    int t = threadIdx.x;
    int base = t * 10;
    int loc[10], run = 0;
    #pragma unroll
    for (int i = 0; i < 10; i++) {
        int idx = base + i;
        int v = (idx < N_NODES) ? deg[idx] : 0;
        loc[i] = run; run += v;
    }
    s[t] = run;
    __syncthreads();
    for (int off = 1; off < 1024; off <<= 1) {
        int xv = (t >= off) ? s[t - off] : 0;
        __syncthreads();
        s[t] += xv;
        __syncthreads();
    }
    int excl = s[t] - run;
    #pragma unroll
    for (int i = 0; i < 10; i++) {
        int idx = base + i;
        if (idx <= N_NODES) rs[idx] = excl + loc[i];
    }
}

__global__ void k_fill(const int* ei, const int* rs, int* cur, int* elist) {
    int e = blockIdx.x * blockDim.x + threadIdx.x;
    if (e >= E2) return;
    int s, d;
    if (e < E_EDGES) { s = ei[e]; d = ei[E_EDGES + e]; }
    else { s = d = e - E_EDGES; }
    int pos = atomicAdd(&cur[d], 1);
    elist[rs[d] + pos] = s;
}

// ---------------- weight preprocessing ----------------
__global__ void k_vw(const float* Wsrc, const float* Wdst,
                     const float* att_src, const float* att_dst,
                     float* vsrc, float* vdst) {
    int l = blockIdx.x;
    int t = threadIdx.x;           // 512
    int head = t >> 7, j = t & 127;
    const float* Ws = Wsrc + (size_t)l * H * HD;
    const float* Wd = Wdst + (size_t)l * H * HD;
    const float* As = att_src + (size_t)l * HEADS * H;
    const float* Ad = att_dst + (size_t)l * HEADS * H;
    float ss = 0.f, sd = 0.f;
    for (int k = 0; k < H; k++) {
        ss += Ws[(size_t)j * HD + head * H + k] * As[head * H + k];
        sd += Wd[(size_t)j * HD + head * H + k] * Ad[head * H + k];
    }
    vsrc[(size_t)l * HD + head * H + j] = ss;
    vdst[(size_t)l * HD + head * H + j] = sd;
}

// pack Wsrc [L][128k][512col] f32 -> B-frag layout [L][nt32][ks4][lane64][j8] bf16
__global__ void k_pack_src(const float* W, ushort_t* Wp) {
    int idx = blockIdx.x * 256 + threadIdx.x;           // 16*65536 total
    int l = idx >> 16, rem = idx & 65535;
    int k = rem >> 9, col = rem & 511;
    float v = W[(size_t)l * H * HD + (size_t)k * HD + col];
    int nt = col >> 4, ks = k >> 5, lhi = (k >> 3) & 3, llo = col & 15, j = k & 7;
    Wp[(size_t)l * 65536 + (((size_t)(nt * 4 + ks) * 64) + lhi * 16 + llo) * 8 + j] = f2b(v);
}

// pack Wout [L][512k][128col] f32 -> [L][nt8][ks16][lane64][j8] bf16
__global__ void k_pack_out(const float* W, ushort_t* Wp) {
    int idx = blockIdx.x * 256 + threadIdx.x;           // 16*65536 total
    int l = idx >> 16, rem = idx & 65535;
    int k = rem >> 7, col = rem & 127;
    float v = W[(size_t)l * HD * H + (size_t)k * H + col];
    int nt = col >> 4, ks = k >> 5, lhi = (k >> 3) & 3, llo = col & 15, j = k & 7;
    Wp[(size_t)l * 65536 + (((size_t)(nt * 16 + ks) * 64) + lhi * 16 + llo) * 8 + j] = f2b(v);
}

// pack W_in [256k][128col] f32 -> [nt8][ks8][lane64][j8] bf16
__global__ void k_pack_win(const float* W, ushort_t* Wp) {
    int idx = blockIdx.x * 256 + threadIdx.x;           // 32768 total
    int k = idx >> 7, col = idx & 127;
    float v = W[(size_t)k * H + col];
    int nt = col >> 4, ks = k >> 5, lhi = (k >> 3) & 3, llo = col & 15, j = k & 7;
    Wp[(((size_t)(nt * 8 + ks) * 64) + lhi * 16 + llo) * 8 + j] = f2b(v);
}

// pack alpha tile: B[k][col]: col<4 -> vsrc[head=col], col in 4..7 -> vdst, else 0
__global__ void k_pack_alpha(const float* vsrc, const float* vdst, ushort_t* Ap) {
    int idx = blockIdx.x * 256 + threadIdx.x;           // 16*2048 total
    int l = idx >> 11, r = idx & 2047;
    int ks = r >> 9, lane = (r >> 3) & 63, j = r & 7;
    int col = lane & 15;
    int k = ks * 32 + (lane >> 4) * 8 + j;
    float v = 0.f;
    if (col < 4)      v = vsrc[(size_t)l * HD + col * H + k];
    else if (col < 8) v = vdst[(size_t)l * HD + (col - 4) * H + k];
    Ap[idx] = f2b(v);
}

// ---------------- input layer: MFMA, 16 rows/block, 625 blocks ----------------
__global__ __launch_bounds__(256) void k_in_mfma(
        const float* __restrict__ x, const ushort_t* __restrict__ WpI,
        const float* __restrict__ b_in, const float* __restrict__ lnw,
        const float* __restrict__ lnb, float* __restrict__ h, ushort_t* __restrict__ hb) {
    __shared__ float part1[4][16], part2[4][16];
    int t = threadIdx.x, w = t >> 6, lane = t & 63;
    int row0 = blockIdx.x * 16;
    int ar = lane & 15, ac = (lane >> 4) * 8;
    short8 a[8];
    #pragma unroll
    for (int ks = 0; ks < 8; ks++) {
        const float* xp = x + (size_t)(row0 + ar) * D_IN + ks * 32 + ac;
        float4 xa = *(const float4*)xp;
        float4 xb = *(const float4*)(xp + 4);
        u32x4 u;
        u.x = pk2(xa.x, xa.y); u.y = pk2(xa.z, xa.w);
        u.z = pk2(xb.x, xb.y); u.w = pk2(xb.z, xb.w);
        a[ks] = *(short8*)&u;
    }
    const ushort_t* B0 = WpI + ((size_t)(w * 2 + 0) * 8) * 64 * 8;
    const ushort_t* B1 = WpI + ((size_t)(w * 2 + 1) * 8) * 64 * 8;
    f32x4 c0 = {0.f, 0.f, 0.f, 0.f}, c1 = {0.f, 0.f, 0.f, 0.f};
    #pragma unroll
    for (int ks = 0; ks < 8; ks++) {
        short8 b0 = *(const short8*)(B0 + ((size_t)ks * 64 + lane) * 8);
        short8 b1 = *(const short8*)(B1 + ((size_t)ks * 64 + lane) * 8);
        c0 = mfma16(a[ks], b0, c0);
        c1 = mfma16(a[ks], b1, c1);
    }
    int col0 = (w * 2 + 0) * 16 + ar, col1 = (w * 2 + 1) * 16 + ar;
    int rb = (lane >> 4) * 4;
    float v0[4], v1[4];
    #pragma unroll
    for (int r = 0; r < 4; r++) {
        v0[r] = c0[r] + b_in[col0];
        v1[r] = c1[r] + b_in[col1];
        float p1 = v0[r] + v1[r];
        float p2 = v0[r] * v0[r] + v1[r] * v1[r];
        #pragma unroll
        for (int off = 1; off < 16; off <<= 1) {
            p1 += __shfl_xor(p1, off);
            p2 += __shfl_xor(p2, off);
        }
        if (ar == 0) { part1[w][rb + r] = p1; part2[w][rb + r] = p2; }
    }
    __syncthreads();
    #pragma unroll
    for (int r = 0; r < 4; r++) {
        int lr = rb + r;
        int row = row0 + lr;
        float s1 = part1[0][lr] + part1[1][lr] + part1[2][lr] + part1[3][lr];
        float s2 = part2[0][lr] + part2[1][lr] + part2[2][lr] + part2[3][lr];
        float m = s1 * (1.f / 128.f);
        float var = s2 * (1.f / 128.f) - m * m;
        float is = rsqrtf(var + EPS);
        float y0 = fmaxf((v0[r] - m) * is * lnw[col0] + lnb[col0], 0.f);
        float y1 = fmaxf((v1[r] - m) * is * lnw[col1] + lnb[col1], 0.f);
        h[(size_t)row * H + col0] = y0;
        h[(size_t)row * H + col1] = y1;
        hb[(size_t)row * H + col0] = f2b(y0);
        hb[(size_t)row * H + col1] = f2b(y1);
    }
}

// ---------------- S = hb @ Wsrc (MFMA) + fused alpha ----------------
// block 256 = 4 waves; 32 rows; wave w owns cols [w*128, w*128+128); buffers padded
__global__ __launch_bounds__(256) void k_src_mfma(
        const ushort_t* __restrict__ hb, const ushort_t* __restrict__ Wp,
        const ushort_t* __restrict__ Ap, ushort_t* __restrict__ S,
        float* __restrict__ as_, float* __restrict__ ad_, int l) {
    int t = threadIdx.x, w = t >> 6, lane = t & 63;
    int row0 = blockIdx.x * 32;
    const ushort_t* WL = Wp + (size_t)l * 65536;
    int ar = lane & 15, ac = (lane >> 4) * 8;
    short8 a[2][4];
    #pragma unroll
    for (int mt = 0; mt < 2; mt++)
        #pragma unroll
        for (int ks = 0; ks < 4; ks++)
            a[mt][ks] = *(const short8*)(hb + (size_t)(row0 + mt * 16 + ar) * H + ks * 32 + ac);
    int rb = row0 + (lane >> 4) * 4;
    #pragma unroll
    for (int nt = 0; nt < 8; nt++) {
        int ntg = w * 8 + nt;
        f32x4 c0 = {0.f, 0.f, 0.f, 0.f}, c1 = {0.f, 0.f, 0.f, 0.f};
        #pragma unroll
        for (int ks = 0; ks < 4; ks++) {
            short8 b = *(const short8*)(WL + ((size_t)(ntg * 4 + ks) * 64 + lane) * 8);
            c0 = mfma16(a[0][ks], b, c0);
            c1 = mfma16(a[1][ks], b, c1);
        }
        int col = ntg * 16 + ar;
        #pragma unroll
        for (int r = 0; r < 4; r++) {
            S[(size_t)(rb + r) * HD + col]      = f2b(c0[r]);
            S[(size_t)(rb + 16 + r) * HD + col] = f2b(c1[r]);
        }
    }
    if (w == 0) {   // fused alpha: one extra 16-col B tile (cols 0-3=asrc, 4-7=adst)
        const ushort_t* AL = Ap + (size_t)l * 2048;
        f32x4 c0 = {0.f, 0.f, 0.f, 0.f}, c1 = {0.f, 0.f, 0.f, 0.f};
        #pragma unroll
        for (int ks = 0; ks < 4; ks++) {
            short8 b = *(const short8*)(AL + ((size_t)ks * 64 + lane) * 8);
            c0 = mfma16(a[0][ks], b, c0);
            c1 = mfma16(a[1][ks], b, c1);
        }
        if (ar < 8) {
            float* dst = (ar < 4) ? as_ : ad_;
            int cc = ar & 3;
            #pragma unroll
            for (int r = 0; r < 4; r++) {
                dst[(rb + r) * 4 + cc]      = c0[r];
                dst[(rb + 16 + r) * 4 + cc] = c1[r];
            }
        }
    }
}

// ---------------- fused aggregation + out-GEMM + residual + LN + relu ----------------
#define ACC1(uv, wt) do { \
    acc[0] += (wt) * __uint_as_float((uv).x << 16); \
    acc[1] += (wt) * __uint_as_float((uv).x & 0xffff0000u); \
    acc[2] += (wt) * __uint_as_float((uv).y << 16); \
    acc[3] += (wt) * __uint_as_float((uv).y & 0xffff0000u); \
    acc[4] += (wt) * __uint_as_float((uv).z << 16); \
    acc[5] += (wt) * __uint_as_float((uv).z & 0xffff0000u); \
    acc[6] += (wt) * __uint_as_float((uv).w << 16); \
    acc[7] += (wt) * __uint_as_float((uv).w & 0xffff0000u); \
} while (0)

__global__ __launch_bounds__(256) void k_aggout(
        const ushort_t* __restrict__ S, const float4* __restrict__ as4,
        const float4* __restrict__ ad4, const int* __restrict__ rs,
        const int* __restrict__ elist, const ushort_t* __restrict__ Wp,
        const float* __restrict__ bout, const float* __restrict__ lnw,
        const float* __restrict__ lnb, float* __restrict__ h,
        ushort_t* __restrict__ hb, int l) {
    __shared__ ushort_t frag[16 * 64 * 8];      // 16KB, granule (l,ks) at l*16+(ks^(l&15))
    __shared__ int sl[4][64];
    __shared__ float wl[4][64][4];
    __shared__ float part1[4][16], part2[4][16];
    int t = threadIdx.x, w = t >> 6, lane = t & 63;
    int base = blockIdx.x * 16;
    int head = lane >> 4;

    // ---- phase 1: aggregate 4 nodes per wave, 4-deep pipelined gather ----
    for (int q = 0; q < 4; q++) {
        int r = w * 4 + q;
        int node = base + r;
        int start = rs[node], end = rs[node + 1];
        float4 adv = ad4[node];
        float acc[8];
        #pragma unroll
        for (int i = 0; i < 8; i++) acc[i] = 0.f;
        for (int c0 = start; c0 < end; c0 += 64) {
            int cnt = min(64, end - c0);
            if (lane < cnt) {
                int s = elist[c0 + lane];
                sl[w][lane] = s;
                float4 av = as4[s];
                float l0 = av.x + adv.x, l1 = av.y + adv.y, l2 = av.z + adv.z, l3 = av.w + adv.w;
                l0 = (l0 > 0.f) ? l0 : 0.2f * l0;
                l1 = (l1 > 0.f) ? l1 : 0.2f * l1;
                l2 = (l2 > 0.f) ? l2 : 0.2f * l2;
                l3 = (l3 > 0.f) ? l3 : 0.2f * l3;
                float mx = fmaxf(fmaxf(l0, l1), fmaxf(l2, l3));
                float e0 = expf(l0 - mx), e1 = expf(l1 - mx), e2 = expf(l2 - mx), e3 = expf(l3 - mx);
                float inv = 1.f / (e0 + e1 + e2 + e3);
                wl[w][lane][0] = e0 * inv;
                wl[w][lane][1] = e1 * inv;
                wl[w][lane][2] = e2 * inv;
                wl[w][lane][3] = e3 * inv;
            }
            __asm__ volatile("s_waitcnt lgkmcnt(0)" ::: "memory");
            int j = 0;
            if (cnt >= 4) {
                u32x4 b0, b1, b2, b3;
                float q0, q1, q2, q3;
                {
                    int s0 = sl[w][0], s1 = sl[w][1], s2 = sl[w][2], s3 = sl[w][3];
                    q0 = wl[w][0][head]; q1 = wl[w][1][head];
                    q2 = wl[w][2][head]; q3 = wl[w][3][head];
                    b0 = *(const u32x4*)(S + (size_t)s0 * HD + lane * 8);
                    b1 = *(const u32x4*)(S + (size_t)s1 * HD + lane * 8);
                    b2 = *(const u32x4*)(S + (size_t)s2 * HD + lane * 8);
                    b3 = *(const u32x4*)(S + (size_t)s3 * HD + lane * 8);
                }
                for (j = 4; j + 3 < cnt; j += 4) {
                    int s0 = sl[w][j], s1 = sl[w][j + 1], s2 = sl[w][j + 2], s3 = sl[w][j + 3];
                    u32x4 n0 = *(const u32x4*)(S + (size_t)s0 * HD + lane * 8);
                    u32x4 n1 = *(const u32x4*)(S + (size_t)s1 * HD + lane * 8);
                    u32x4 n2 = *(const u32x4*)(S + (size_t)s2 * HD + lane * 8);
                    u32x4 n3 = *(const u32x4*)(S + (size_t)s3 * HD + lane * 8);
                    float r0 = wl[w][j][head], r1 = wl[w][j + 1][head];
                    float r2 = wl[w][j + 2][head], r3 = wl[w][j + 3][head];
                    ACC1(b0, q0); ACC1(b1, q1); ACC1(b2, q2); ACC1(b3, q3);
                    b0 = n0; q0 = r0; b1 = n1; q1 = r1;
                    b2 = n2; q2 = r2; b3 = n3; q3 = r3;
                }
                ACC1(b0, q0); ACC1(b1, q1); ACC1(b2, q2); ACC1(b3, q3);
            }
            for (; j < cnt; j++) {
                int s = sl[w][j];
                float wt = wl[w][j][head];
                u32x4 uv = *(const u32x4*)(S + (size_t)s * HD + lane * 8);
                ACC1(uv, wt);
            }
        }
        u32x4 o;
        o.x = pk2(acc[0], acc[1]);
        o.y = pk2(acc[2], acc[3]);
        o.z = pk2(acc[4], acc[5]);
        o.w = pk2(acc[6], acc[7]);
        int gidx = ((lane & 3) * 16 + r) * 16 + ((lane >> 2) ^ r);
        *(u32x4*)((char*)frag + gidx * 16) = o;
    }
    __syncthreads();

    // ---- phase 2: out-GEMM 16x128, K=512 ----
    const ushort_t* WL = Wp + (size_t)l * 65536;
    short8 a[16];
    #pragma unroll
    for (int ks = 0; ks < 16; ks++) {
        int gidx = lane * 16 + (ks ^ (lane & 15));
        a[ks] = *(const short8*)((const char*)frag + gidx * 16);
    }
    int ar = lane & 15;
    f32x4 c0 = {0.f, 0.f, 0.f, 0.f}, c1 = {0.f, 0.f, 0.f, 0.f};
    #pragma unroll
    for (int ks = 0; ks < 16; ks++) {
        short8 b0 = *(const short8*)(WL + ((size_t)((w * 2 + 0) * 16 + ks) * 64 + lane) * 8);
        short8 b1 = *(const short8*)(WL + ((size_t)((w * 2 + 1) * 16 + ks) * 64 + lane) * 8);
        c0 = mfma16(a[ks], b0, c0);
        c1 = mfma16(a[ks], b1, c1);
    }

    // ---- phase 3: bias + residual + LN + relu ----
    const float* bo = bout + (size_t)l * H;
    const float* gw = lnw + (size_t)l * H;
    const float* gb = lnb + (size_t)l * H;
    int col0 = (w * 2 + 0) * 16 + ar;
    int col1 = (w * 2 + 1) * 16 + ar;
    int rb = (lane >> 4) * 4;
    float v0[4], v1[4];
    #pragma unroll
    for (int r = 0; r < 4; r++) {
        int row = base + rb + r;
        v0[r] = c0[r] + bo[col0] + h[(size_t)row * H + col0];
        v1[r] = c1[r] + bo[col1] + h[(size_t)row * H + col1];
        float p1 = v0[r] + v1[r];
        float p2 = v0[r] * v0[r] + v1[r] * v1[r];
        #pragma unroll
        for (int off = 1; off < 16; off <<= 1) {
            p1 += __shfl_xor(p1, off);
            p2 += __shfl_xor(p2, off);
        }
        if (ar == 0) { part1[w][rb + r] = p1; part2[w][rb + r] = p2; }
    }
    __syncthreads();
    #pragma unroll
    for (int r = 0; r < 4; r++) {
        int lr = rb + r;
        int row = base + lr;
        float s1 = part1[0][lr] + part1[1][lr] + part1[2][lr] + part1[3][lr];
        float s2 = part2[0][lr] + part2[1][lr] + part2[2][lr] + part2[3][lr];
        float m = s1 * (1.f / 128.f);
        float var = s2 * (1.f / 128.f) - m * m;
        float is = rsqrtf(var + EPS);
        float y0 = fmaxf((v0[r] - m) * is * gw[col0] + gb[col0], 0.f);
        float y1 = fmaxf((v1[r] - m) * is * gw[col1] + gb[col1], 0.f);
        h[(size_t)row * H + col0] = y0;
        h[(size_t)row * H + col1] = y1;
        hb[(size_t)row * H + col0] = f2b(y0);
        hb[(size_t)row * H + col1] = f2b(y1);
    }
}

// ---------------- pooling + MLPs ----------------
__global__ void k_pool(const float* __restrict__ h, const int* __restrict__ batch,
                       unsigned* __restrict__ g) {
    __shared__ float lm[G_GRAPHS][H];
    int t = threadIdx.x;
    #pragma unroll
    for (int i = 0; i < G_GRAPHS; i++) lm[i][t] = 0.f;
    int n0 = blockIdx.x * 100, n1 = n0 + 100;
    for (int n = n0; n < n1; n++) {
        int b = batch[n];
        lm[b][t] = fmaxf(lm[b][t], h[(size_t)n * H + t]);
    }
    #pragma unroll
    for (int i = 0; i < G_GRAPHS; i++)
        atomicMax(&g[i * H + t], __float_as_uint(lm[i][t]));
}

__global__ void k_mlp1(const unsigned* __restrict__ g, const float* __restrict__ Wp1,
                       const float* __restrict__ bp1, float* __restrict__ g1) {
    __shared__ float gs[H];
    int gr = blockIdx.x >> 2, ch = blockIdx.x & 3;
    int t = threadIdx.x;                        // 256
    if (t < H) gs[t] = __uint_as_float(g[gr * H + t]);
    __syncthreads();
    int col = ch * 256 + t;
    float acc = 0.f;
    for (int k = 0; k < H; k++) acc += gs[k] * Wp1[(size_t)k * OUT_DIM + col];
    acc += bp1[col];
    g1[(size_t)gr * OUT_DIM + col] = fmaxf(acc, 0.f);
}

__global__ void k_mlp2(const float* __restrict__ g1, const float* __restrict__ Wp2,
                       const float* __restrict__ bp2, float* __restrict__ out) {
    __shared__ float gs[OUT_DIM];
    __shared__ float part[4][64];
    int gr = blockIdx.x >> 4, ch = blockIdx.x & 15;
    int t = threadIdx.x;                        // 256
    int ci = t & 63, si = t >> 6;
    for (int i = t; i < OUT_DIM; i += 256) gs[i] = g1[(size_t)gr * OUT_DIM + i];
    __syncthreads();
    int col = ch * 64 + ci;
    float acc = 0.f;
    for (int k = si * 256; k < si * 256 + 256; k++)
        acc += gs[k] * Wp2[(size_t)k * OUT_DIM + col];
    part[si][ci] = acc;
    __syncthreads();
    if (si == 0) {
        float r = part[0][ci] + part[1][ci] + part[2][ci] + part[3][ci] + bp2[col];
        out[(size_t)gr * OUT_DIM + col] = r;
    }
}

// ---------------- launch ----------------
extern "C" void kernel_launch(void* const* d_in, const int* in_sizes, int n_in,
                              void* d_out, int out_size, void* d_ws, size_t ws_size,
                              hipStream_t stream) {
    const float* x       = (const float*)d_in[0];
    const int*   ei      = (const int*)d_in[1];     // int32
    const int*   batch   = (const int*)d_in[2];     // int32
    const float* W_in    = (const float*)d_in[3];
    const float* b_in    = (const float*)d_in[4];
    const float* ln_in_w = (const float*)d_in[5];
    const float* ln_in_b = (const float*)d_in[6];
    const float* Wsrc    = (const float*)d_in[7];
    const float* Wdst    = (const float*)d_in[8];
    const float* att_src = (const float*)d_in[9];
    const float* att_dst = (const float*)d_in[10];
    const float* Wout    = (const float*)d_in[11];
    const float* bout    = (const float*)d_in[12];
    const float* ln_w    = (const float*)d_in[13];
    const float* ln_b    = (const float*)d_in[14];
    const float* Wp1     = (const float*)d_in[15];
    const float* bp1     = (const float*)d_in[16];
    const float* Wp2     = (const float*)d_in[17];
    const float* bp2     = (const float*)d_in[18];

    char* w = (char*)d_ws;
    auto alloc = [&](size_t bytes) { void* p = w; w += (bytes + 255) & ~(size_t)255; return p; };
    float*     h     = (float*)alloc((size_t)N_NODES * H * 4);
    ushort_t*  hb    = (ushort_t*)alloc((size_t)SPAD * H * 2);
    ushort_t*  S     = (ushort_t*)alloc((size_t)SPAD * HD * 2);
    float*     as_   = (float*)alloc((size_t)SPAD * HEADS * 4);
    float*     ad_   = (float*)alloc((size_t)SPAD * HEADS * 4);
    float*     vsrc  = (float*)alloc((size_t)L_LAYERS * HD * 4);
    float*     vdst  = (float*)alloc((size_t)L_LAYERS * HD * 4);
    ushort_t*  WpS   = (ushort_t*)alloc((size_t)L_LAYERS * 65536 * 2);
    ushort_t*  WpO   = (ushort_t*)alloc((size_t)L_LAYERS * 65536 * 2);
    ushort_t*  WpI   = (ushort_t*)alloc((size_t)D_IN * H * 2);
    ushort_t*  Ap    = (ushort_t*)alloc((size_t)L_LAYERS * 2048 * 2);
    int*       deg   = (int*)alloc((size_t)N_NODES * 4);
    int*       rs    = (int*)alloc((size_t)(N_NODES + 1) * 4);
    int*       cur   = (int*)alloc((size_t)N_NODES * 4);
    int*       elist = (int*)alloc((size_t)E2 * 4);
    unsigned*  g     = (unsigned*)alloc((size_t)G_GRAPHS * H * 4);
    float*     g1    = (float*)alloc((size_t)G_GRAPHS * OUT_DIM * 4);

    k_zero<<<40, 256, 0, stream>>>(deg, cur, g);
    k_count<<<(E2 + 255) / 256, 256, 0, stream>>>(ei, deg);
    k_scan<<<1, 1024, 0, stream>>>(deg, rs);
    k_fill<<<(E2 + 255) / 256, 256, 0, stream>>>(ei, rs, cur, elist);
    k_vw<<<L_LAYERS, 512, 0, stream>>>(Wsrc, Wdst, att_src, att_dst, vsrc, vdst);
    k_pack_src<<<4096, 256, 0, stream>>>(Wsrc, WpS);
    k_pack_out<<<4096, 256, 0, stream>>>(Wout, WpO);
    k_pack_win<<<128, 256, 0, stream>>>(W_in, WpI);
    k_pack_alpha<<<128, 256, 0, stream>>>(vsrc, vdst, Ap);
    k_in_mfma<<<N_NODES / 16, 256, 0, stream>>>(x, WpI, b_in, ln_in_w, ln_in_b, h, hb);

    for (int l = 0; l < L_LAYERS; l++) {
        k_src_mfma<<<313, 256, 0, stream>>>(hb, WpS, Ap, S, as_, ad_, l);
        k_aggout<<<N_NODES / 16, 256, 0, stream>>>(S, (const float4*)as_, (const float4*)ad_,
                                                   rs, elist, WpO, bout, ln_w, ln_b, h, hb, l);
    }

    k_pool<<<100, 128, 0, stream>>>(h, batch, g);
    k_mlp1<<<G_GRAPHS * 4, 256, 0, stream>>>(g, Wp1, bp1, g1);
    k_mlp2<<<G_GRAPHS * 16, 256, 0, stream>>>(g1, Wp2, bp2, (float*)d_out);
}

// Round 6
// 719.811 us; speedup vs baseline: 3.0059x; 1.1062x over previous
//
#include <hip/hip_runtime.h>
#include <hip/hip_bf16.h>

#define N_NODES 10000
#define E_EDGES 160000
#define E2 (E_EDGES + N_NODES)
#define D_IN 256
#define H 128
#define HEADS 4
#define HD 512
#define L_LAYERS 16
#define OUT_DIM 1024
#define G_GRAPHS 8
#define EPS 1e-5f
#define SPAD 10016

typedef unsigned short ushort_t;
typedef __attribute__((ext_vector_type(8))) short short8;
typedef __attribute__((ext_vector_type(4))) float f32x4;
typedef __attribute__((ext_vector_type(4))) unsigned u32x4;

__device__ __forceinline__ f32x4 mfma16(short8 a, short8 b, f32x4 c) {
    return __builtin_amdgcn_mfma_f32_16x16x32_bf16(a, b, c, 0, 0, 0);
}
__device__ __forceinline__ unsigned short f2b(float f) {   // f32 -> bf16 bits, RNE
    unsigned u = __float_as_uint(f);
    u += 0x7fffu + ((u >> 16) & 1u);
    return (unsigned short)(u >> 16);
}
__device__ __forceinline__ unsigned pk2(float lo, float hi) {  // 2xf32 -> packed bf16x2
    __hip_bfloat162 p = __float22bfloat162_rn(make_float2(lo, hi));
    return *(unsigned*)&p;
}

// ---------------- setup: CSR build (int32 edges) ----------------
__global__ void k_zero(int* deg, int* cur, unsigned* g) {
    int i = blockIdx.x * blockDim.x + threadIdx.x;
    if (i < N_NODES) { deg[i] = 0; cur[i] = 0; }
    if (i < G_GRAPHS * H) g[i] = 0u;
}

__global__ void k_count(const int* ei, int* deg) {
    int e = blockIdx.x * blockDim.x + threadIdx.x;
    if (e >= E2) return;
    int d = (e < E_EDGES) ? ei[E_EDGES + e] : (e - E_EDGES);
    atomicAdd(&deg[d], 1);
}

__global__ void k_scan(const int* deg, int* rs) {   // 1 block x 1024, 10 elems/thread
    __shared__ int s[1024];
    int t = threadIdx.x;
    int base = t * 10;
    int loc[10], run = 0;
    #pragma unroll
    for (int i = 0; i < 10; i++) {
        int idx = base + i;
        int v = (idx < N_NODES) ? deg[idx] : 0;
        loc[i] = run; run += v;
    }
    s[t] = run;
    __syncthreads();
    for (int off = 1; off < 1024; off <<= 1) {
        int xv = (t >= off) ? s[t - off] : 0;
        __syncthreads();
        s[t] += xv;
        __syncthreads();
    }
    int excl = s[t] - run;
    #pragma unroll
    for (int i = 0; i < 10; i++) {
        int idx = base + i;
        if (idx <= N_NODES) rs[idx] = excl + loc[i];
    }
}

__global__ void k_fill(const int* ei, const int* rs, int* cur, int* elist) {
    int e = blockIdx.x * blockDim.x + threadIdx.x;
    if (e >= E2) return;
    int s, d;
    if (e < E_EDGES) { s = ei[e]; d = ei[E_EDGES + e]; }
    else { s = d = e - E_EDGES; }
    int pos = atomicAdd(&cur[d], 1);
    elist[rs[d] + pos] = s;
}

// ---------------- weight preprocessing ----------------
// vsrc[l][head*H + j] = sum_k Wsrc[l][j][head*H+k] * att_src[l][head][k]
__global__ void k_vw(const float* Wsrc, const float* Wdst,
                     const float* att_src, const float* att_dst,
                     float* vsrc, float* vdst) {
    int l = blockIdx.x;
    int t = threadIdx.x;           // 512
    int head = t >> 7, j = t & 127;
    const float* Ws = Wsrc + (size_t)l * H * HD;
    const float* Wd = Wdst + (size_t)l * H * HD;
    const float* As = att_src + (size_t)l * HEADS * H;
    const float* Ad = att_dst + (size_t)l * HEADS * H;
    float ss = 0.f, sd = 0.f;
    for (int k = 0; k < H; k++) {
        ss += Ws[(size_t)j * HD + head * H + k] * As[head * H + k];
        sd += Wd[(size_t)j * HD + head * H + k] * Ad[head * H + k];
    }
    vsrc[(size_t)l * HD + head * H + j] = ss;
    vdst[(size_t)l * HD + head * H + j] = sd;
}

// M[l][h*128+k][o] = sum_c Wsrc[l][k][h*128+c] * Wout[l][h*128+c][o]
__global__ __launch_bounds__(256) void k_mm(const float* __restrict__ Wsrc,
        const float* __restrict__ Wout, float* __restrict__ M) {
    int bid = blockIdx.x;              // ((l*4+h)*4 + kq), 256 blocks
    int kq = bid & 3, h = (bid >> 2) & 3, l = bid >> 4;
    int t = threadIdx.x;
    int o = t & 127, kh = t >> 7;
    const float* Ws = Wsrc + (size_t)l * H * HD + h * 128;
    const float* Wo = Wout + (size_t)l * HD * H + (size_t)h * 128 * H;
    for (int r = 0; r < 16; r++) {
        int k = kq * 32 + kh * 16 + r;
        float acc = 0.f;
        for (int c = 0; c < 128; c++)
            acc += Ws[(size_t)k * HD + c] * Wo[(size_t)c * H + o];
        M[(size_t)l * HD * H + (size_t)(h * 128 + k) * H + o] = acc;
    }
}

// pack [L][512k][128col] f32 -> B-frag layout [L][nt8][ks16][lane64][j8] bf16
__global__ void k_pack_out(const float* W, ushort_t* Wp) {
    int idx = blockIdx.x * 256 + threadIdx.x;           // 16*65536 total
    int l = idx >> 16, rem = idx & 65535;
    int k = rem >> 7, col = rem & 127;
    float v = W[(size_t)l * HD * H + (size_t)k * H + col];
    int nt = col >> 4, ks = k >> 5, lhi = (k >> 3) & 3, llo = col & 15, j = k & 7;
    Wp[(size_t)l * 65536 + (((size_t)(nt * 16 + ks) * 64) + lhi * 16 + llo) * 8 + j] = f2b(v);
}

// pack W_in [256k][128col] f32 -> [nt8][ks8][lane64][j8] bf16
__global__ void k_pack_win(const float* W, ushort_t* Wp) {
    int idx = blockIdx.x * 256 + threadIdx.x;           // 32768 total
    int k = idx >> 7, col = idx & 127;
    float v = W[(size_t)k * H + col];
    int nt = col >> 4, ks = k >> 5, lhi = (k >> 3) & 3, llo = col & 15, j = k & 7;
    Wp[(((size_t)(nt * 8 + ks) * 64) + lhi * 16 + llo) * 8 + j] = f2b(v);
}

// ---------------- input layer: MFMA, 16 rows/block, 625 blocks ----------------
__global__ __launch_bounds__(256) void k_in_mfma(
        const float* __restrict__ x, const ushort_t* __restrict__ WpI,
        const float* __restrict__ b_in, const float* __restrict__ lnw,
        const float* __restrict__ lnb, float* __restrict__ h, ushort_t* __restrict__ hb) {
    __shared__ float part1[4][16], part2[4][16];
    int t = threadIdx.x, w = t >> 6, lane = t & 63;
    int row0 = blockIdx.x * 16;
    int ar = lane & 15, ac = (lane >> 4) * 8;
    short8 a[8];
    #pragma unroll
    for (int ks = 0; ks < 8; ks++) {
        const float* xp = x + (size_t)(row0 + ar) * D_IN + ks * 32 + ac;
        float4 xa = *(const float4*)xp;
        float4 xb = *(const float4*)(xp + 4);
        u32x4 u;
        u.x = pk2(xa.x, xa.y); u.y = pk2(xa.z, xa.w);
        u.z = pk2(xb.x, xb.y); u.w = pk2(xb.z, xb.w);
        a[ks] = *(short8*)&u;
    }
    const ushort_t* B0 = WpI + ((size_t)(w * 2 + 0) * 8) * 64 * 8;
    const ushort_t* B1 = WpI + ((size_t)(w * 2 + 1) * 8) * 64 * 8;
    f32x4 c0 = {0.f, 0.f, 0.f, 0.f}, c1 = {0.f, 0.f, 0.f, 0.f};
    #pragma unroll
    for (int ks = 0; ks < 8; ks++) {
        short8 b0 = *(const short8*)(B0 + ((size_t)ks * 64 + lane) * 8);
        short8 b1 = *(const short8*)(B1 + ((size_t)ks * 64 + lane) * 8);
        c0 = mfma16(a[ks], b0, c0);
        c1 = mfma16(a[ks], b1, c1);
    }
    int col0 = (w * 2 + 0) * 16 + ar, col1 = (w * 2 + 1) * 16 + ar;
    int rb = (lane >> 4) * 4;
    float v0[4], v1[4];
    #pragma unroll
    for (int r = 0; r < 4; r++) {
        v0[r] = c0[r] + b_in[col0];
        v1[r] = c1[r] + b_in[col1];
        float p1 = v0[r] + v1[r];
        float p2 = v0[r] * v0[r] + v1[r] * v1[r];
        #pragma unroll
        for (int off = 1; off < 16; off <<= 1) {
            p1 += __shfl_xor(p1, off);
            p2 += __shfl_xor(p2, off);
        }
        if (ar == 0) { part1[w][rb + r] = p1; part2[w][rb + r] = p2; }
    }
    __syncthreads();
    #pragma unroll
    for (int r = 0; r < 4; r++) {
        int lr = rb + r;
        int row = row0 + lr;
        float s1 = part1[0][lr] + part1[1][lr] + part1[2][lr] + part1[3][lr];
        float s2 = part2[0][lr] + part2[1][lr] + part2[2][lr] + part2[3][lr];
        float m = s1 * (1.f / 128.f);
        float var = s2 * (1.f / 128.f) - m * m;
        float is = rsqrtf(var + EPS);
        float y0 = fmaxf((v0[r] - m) * is * lnw[col0] + lnb[col0], 0.f);
        float y1 = fmaxf((v1[r] - m) * is * lnw[col1] + lnb[col1], 0.f);
        h[(size_t)row * H + col0] = y0;
        h[(size_t)row * H + col1] = y1;
        hb[(size_t)row * H + col0] = f2b(y0);
        hb[(size_t)row * H + col1] = f2b(y1);
    }
}

// ---------------- alphas: one wave per node (f32, exact) ----------------
__global__ __launch_bounds__(256) void k_alpha(const float* __restrict__ h,
        const float* __restrict__ vsrc, const float* __restrict__ vdst,
        float* __restrict__ as_, float* __restrict__ ad_, int l) {
    int wid = threadIdx.x >> 6, lane = threadIdx.x & 63;
    int n = blockIdx.x * 4 + wid;
    float h0 = h[(size_t)n * H + lane];
    float h1 = h[(size_t)n * H + 64 + lane];
    const float* vs = vsrc + (size_t)l * HD;
    const float* vd = vdst + (size_t)l * HD;
    #pragma unroll
    for (int d = 0; d < HEADS; d++) {
        float p = h0 * vs[d * H + lane] + h1 * vs[d * H + 64 + lane];
        float q = h0 * vd[d * H + lane] + h1 * vd[d * H + 64 + lane];
        #pragma unroll
        for (int off = 32; off > 0; off >>= 1) {
            p += __shfl_down(p, off);
            q += __shfl_down(q, off);
        }
        if (lane == 0) { as_[n * HEADS + d] = p; ad_[n * HEADS + d] = q; }
    }
}

// ---------------- fused T-aggregation + folded out-GEMM + residual + LN + relu ----------------
// T[d][h*128+k] = sum_e w_e^h * hb[s_e][k]; out = T @ M (M = Wsrc_h@Wout_h folded)
#define ACC1(uv, wt) do { \
    acc[0] += (wt) * __uint_as_float((uv).x << 16); \
    acc[1] += (wt) * __uint_as_float((uv).x & 0xffff0000u); \
    acc[2] += (wt) * __uint_as_float((uv).y << 16); \
    acc[3] += (wt) * __uint_as_float((uv).y & 0xffff0000u); \
    acc[4] += (wt) * __uint_as_float((uv).z << 16); \
    acc[5] += (wt) * __uint_as_float((uv).z & 0xffff0000u); \
    acc[6] += (wt) * __uint_as_float((uv).w << 16); \
    acc[7] += (wt) * __uint_as_float((uv).w & 0xffff0000u); \
} while (0)

__global__ __launch_bounds__(256) void k_aggout(
        const ushort_t* __restrict__ hb, const float4* __restrict__ as4,
        const float4* __restrict__ ad4, const int* __restrict__ rs,
        const int* __restrict__ elist, const ushort_t* __restrict__ Wp,
        const float* __restrict__ bout, const float* __restrict__ lnw,
        const float* __restrict__ lnb, float* __restrict__ h,
        ushort_t* __restrict__ hbo, int l) {
    __shared__ ushort_t frag[16 * 64 * 8];      // 16KB, granule row = lhi*16+r, col = ks^r
    __shared__ int sl[4][64];
    __shared__ float wl[4][64][4];
    __shared__ float part1[4][16], part2[4][16];
    int t = threadIdx.x, w = t >> 6, lane = t & 63;
    int base = blockIdx.x * 16;
    int head = lane >> 4;
    int j8 = (lane & 15) * 8;                   // 8 consecutive hb cols per lane

    // ---- phase 1: aggregate T for 4 nodes per wave (gather hb rows, 256B/edge) ----
    for (int q = 0; q < 4; q++) {
        int r = w * 4 + q;
        int node = base + r;
        int start = rs[node], end = rs[node + 1];
        float4 adv = ad4[node];
        float acc[8];
        #pragma unroll
        for (int i = 0; i < 8; i++) acc[i] = 0.f;
        for (int c0 = start; c0 < end; c0 += 64) {
            int cnt = min(64, end - c0);
            if (lane < cnt) {
                int s = elist[c0 + lane];
                sl[w][lane] = s;
                float4 av = as4[s];
                float l0 = av.x + adv.x, l1 = av.y + adv.y, l2 = av.z + adv.z, l3 = av.w + adv.w;
                l0 = (l0 > 0.f) ? l0 : 0.2f * l0;
                l1 = (l1 > 0.f) ? l1 : 0.2f * l1;
                l2 = (l2 > 0.f) ? l2 : 0.2f * l2;
                l3 = (l3 > 0.f) ? l3 : 0.2f * l3;
                float mx = fmaxf(fmaxf(l0, l1), fmaxf(l2, l3));
                float e0 = expf(l0 - mx), e1 = expf(l1 - mx), e2 = expf(l2 - mx), e3 = expf(l3 - mx);
                float inv = 1.f / (e0 + e1 + e2 + e3);
                wl[w][lane][0] = e0 * inv;
                wl[w][lane][1] = e1 * inv;
                wl[w][lane][2] = e2 * inv;
                wl[w][lane][3] = e3 * inv;
            }
            __asm__ volatile("s_waitcnt lgkmcnt(0)" ::: "memory");
            int j = 0;
            if (cnt >= 4) {
                u32x4 b0, b1, b2, b3;
                float q0, q1, q2, q3;
                {
                    int s0 = sl[w][0], s1 = sl[w][1], s2 = sl[w][2], s3 = sl[w][3];
                    q0 = wl[w][0][head]; q1 = wl[w][1][head];
                    q2 = wl[w][2][head]; q3 = wl[w][3][head];
                    b0 = *(const u32x4*)(hb + (size_t)s0 * H + j8);
                    b1 = *(const u32x4*)(hb + (size_t)s1 * H + j8);
                    b2 = *(const u32x4*)(hb + (size_t)s2 * H + j8);
                    b3 = *(const u32x4*)(hb + (size_t)s3 * H + j8);
                }
                for (j = 4; j + 3 < cnt; j += 4) {
                    int s0 = sl[w][j], s1 = sl[w][j + 1], s2 = sl[w][j + 2], s3 = sl[w][j + 3];
                    u32x4 n0 = *(const u32x4*)(hb + (size_t)s0 * H + j8);
                    u32x4 n1 = *(const u32x4*)(hb + (size_t)s1 * H + j8);
                    u32x4 n2 = *(const u32x4*)(hb + (size_t)s2 * H + j8);
                    u32x4 n3 = *(const u32x4*)(hb + (size_t)s3 * H + j8);
                    float r0 = wl[w][j][head], r1 = wl[w][j + 1][head];
                    float r2 = wl[w][j + 2][head], r3 = wl[w][j + 3][head];
                    ACC1(b0, q0); ACC1(b1, q1); ACC1(b2, q2); ACC1(b3, q3);
                    b0 = n0; q0 = r0; b1 = n1; q1 = r1;
                    b2 = n2; q2 = r2; b3 = n3; q3 = r3;
                }
                ACC1(b0, q0); ACC1(b1, q1); ACC1(b2, q2); ACC1(b3, q3);
            }
            for (; j < cnt; j++) {
                int s = sl[w][j];
                float wt = wl[w][j][head];
                u32x4 uv = *(const u32x4*)(hb + (size_t)s * H + j8);
                ACC1(uv, wt);
            }
        }
        // lane holds T[head*128 + j8 .. +7] of node row r
        u32x4 o;
        o.x = pk2(acc[0], acc[1]);
        o.y = pk2(acc[2], acc[3]);
        o.z = pk2(acc[4], acc[5]);
        o.w = pk2(acc[6], acc[7]);
        int ksn = head * 4 + ((lane >> 2) & 3);          // k = head*128+j8 -> ks
        int gidx = ((lane & 3) * 16 + r) * 16 + (ksn ^ r);
        *(u32x4*)((char*)frag + gidx * 16) = o;
    }
    __syncthreads();

    // ---- phase 2: out-GEMM 16x128, K=512 (B = folded M) ----
    const ushort_t* WL = Wp + (size_t)l * 65536;
    short8 a[16];
    #pragma unroll
    for (int ks = 0; ks < 16; ks++) {
        int gidx = lane * 16 + (ks ^ (lane & 15));
        a[ks] = *(const short8*)((const char*)frag + gidx * 16);
    }
    int ar = lane & 15;
    f32x4 c0 = {0.f, 0.f, 0.f, 0.f}, c1 = {0.f, 0.f, 0.f, 0.f};
    #pragma unroll
    for (int ks = 0; ks < 16; ks++) {
        short8 b0 = *(const short8*)(WL + ((size_t)((w * 2 + 0) * 16 + ks) * 64 + lane) * 8);
        short8 b1 = *(const short8*)(WL + ((size_t)((w * 2 + 1) * 16 + ks) * 64 + lane) * 8);
        c0 = mfma16(a[ks], b0, c0);
        c1 = mfma16(a[ks], b1, c1);
    }

    // ---- phase 3: bias + residual + LN + relu ----
    const float* bo = bout + (size_t)l * H;
    const float* gw = lnw + (size_t)l * H;
    const float* gb = lnb + (size_t)l * H;
    int col0 = (w * 2 + 0) * 16 + ar;
    int col1 = (w * 2 + 1) * 16 + ar;
    int rb = (lane >> 4) * 4;
    float v0[4], v1[4];
    #pragma unroll
    for (int r = 0; r < 4; r++) {
        int row = base + rb + r;
        v0[r] = c0[r] + bo[col0] + h[(size_t)row * H + col0];
        v1[r] = c1[r] + bo[col1] + h[(size_t)row * H + col1];
        float p1 = v0[r] + v1[r];
        float p2 = v0[r] * v0[r] + v1[r] * v1[r];
        #pragma unroll
        for (int off = 1; off < 16; off <<= 1) {
            p1 += __shfl_xor(p1, off);
            p2 += __shfl_xor(p2, off);
        }
        if (ar == 0) { part1[w][rb + r] = p1; part2[w][rb + r] = p2; }
    }
    __syncthreads();
    #pragma unroll
    for (int r = 0; r < 4; r++) {
        int lr = rb + r;
        int row = base + lr;
        float s1 = part1[0][lr] + part1[1][lr] + part1[2][lr] + part1[3][lr];
        float s2 = part2[0][lr] + part2[1][lr] + part2[2][lr] + part2[3][lr];
        float m = s1 * (1.f / 128.f);
        float var = s2 * (1.f / 128.f) - m * m;
        float is = rsqrtf(var + EPS);
        float y0 = fmaxf((v0[r] - m) * is * gw[col0] + gb[col0], 0.f);
        float y1 = fmaxf((v1[r] - m) * is * gw[col1] + gb[col1], 0.f);
        h[(size_t)row * H + col0] = y0;
        h[(size_t)row * H + col1] = y1;
        hbo[(size_t)row * H + col0] = f2b(y0);
        hbo[(size_t)row * H + col1] = f2b(y1);
    }
}

// ---------------- pooling + MLPs ----------------
__global__ void k_pool(const float* __restrict__ h, const int* __restrict__ batch,
                       unsigned* __restrict__ g) {
    __shared__ float lm[G_GRAPHS][H];
    int t = threadIdx.x;
    #pragma unroll
    for (int i = 0; i < G_GRAPHS; i++) lm[i][t] = 0.f;
    int n0 = blockIdx.x * 100, n1 = n0 + 100;
    for (int n = n0; n < n1; n++) {
        int b = batch[n];
        lm[b][t] = fmaxf(lm[b][t], h[(size_t)n * H + t]);
    }
    #pragma unroll
    for (int i = 0; i < G_GRAPHS; i++)
        atomicMax(&g[i * H + t], __float_as_uint(lm[i][t]));
}

__global__ void k_mlp1(const unsigned* __restrict__ g, const float* __restrict__ Wp1,
                       const float* __restrict__ bp1, float* __restrict__ g1) {
    __shared__ float gs[H];
    int gr = blockIdx.x >> 2, ch = blockIdx.x & 3;
    int t = threadIdx.x;                        // 256
    if (t < H) gs[t] = __uint_as_float(g[gr * H + t]);
    __syncthreads();
    int col = ch * 256 + t;
    float acc = 0.f;
    for (int k = 0; k < H; k++) acc += gs[k] * Wp1[(size_t)k * OUT_DIM + col];
    acc += bp1[col];
    g1[(size_t)gr * OUT_DIM + col] = fmaxf(acc, 0.f);
}

__global__ void k_mlp2(const float* __restrict__ g1, const float* __restrict__ Wp2,
                       const float* __restrict__ bp2, float* __restrict__ out) {
    __shared__ float gs[OUT_DIM];
    __shared__ float part[4][64];
    int gr = blockIdx.x >> 4, ch = blockIdx.x & 15;
    int t = threadIdx.x;                        // 256
    int ci = t & 63, si = t >> 6;
    for (int i = t; i < OUT_DIM; i += 256) gs[i] = g1[(size_t)gr * OUT_DIM + i];
    __syncthreads();
    int col = ch * 64 + ci;
    float acc = 0.f;
    for (int k = si * 256; k < si * 256 + 256; k++)
        acc += gs[k] * Wp2[(size_t)k * OUT_DIM + col];
    part[si][ci] = acc;
    __syncthreads();
    if (si == 0) {
        float r = part[0][ci] + part[1][ci] + part[2][ci] + part[3][ci] + bp2[col];
        out[(size_t)gr * OUT_DIM + col] = r;
    }
}

// ---------------- launch ----------------
extern "C" void kernel_launch(void* const* d_in, const int* in_sizes, int n_in,
                              void* d_out, int out_size, void* d_ws, size_t ws_size,
                              hipStream_t stream) {
    const float* x       = (const float*)d_in[0];
    const int*   ei      = (const int*)d_in[1];     // int32
    const int*   batch   = (const int*)d_in[2];     // int32
    const float* W_in    = (const float*)d_in[3];
    const float* b_in    = (const float*)d_in[4];
    const float* ln_in_w = (const float*)d_in[5];
    const float* ln_in_b = (const float*)d_in[6];
    const float* Wsrc    = (const float*)d_in[7];
    const float* Wdst    = (const float*)d_in[8];
    const float* att_src = (const float*)d_in[9];
    const float* att_dst = (const float*)d_in[10];
    const float* Wout    = (const float*)d_in[11];
    const float* bout    = (const float*)d_in[12];
    const float* ln_w    = (const float*)d_in[13];
    const float* ln_b    = (const float*)d_in[14];
    const float* Wp1     = (const float*)d_in[15];
    const float* bp1     = (const float*)d_in[16];
    const float* Wp2     = (const float*)d_in[17];
    const float* bp2     = (const float*)d_in[18];

    char* w = (char*)d_ws;
    auto alloc = [&](size_t bytes) { void* p = w; w += (bytes + 255) & ~(size_t)255; return p; };
    float*     h     = (float*)alloc((size_t)N_NODES * H * 4);
    ushort_t*  hb    = (ushort_t*)alloc((size_t)SPAD * H * 2);
    float*     as_   = (float*)alloc((size_t)SPAD * HEADS * 4);
    float*     ad_   = (float*)alloc((size_t)SPAD * HEADS * 4);
    float*     vsrc  = (float*)alloc((size_t)L_LAYERS * HD * 4);
    float*     vdst  = (float*)alloc((size_t)L_LAYERS * HD * 4);
    float*     M     = (float*)alloc((size_t)L_LAYERS * HD * H * 4);
    ushort_t*  WpM   = (ushort_t*)alloc((size_t)L_LAYERS * 65536 * 2);
    ushort_t*  WpI   = (ushort_t*)alloc((size_t)D_IN * H * 2);
    int*       deg   = (int*)alloc((size_t)N_NODES * 4);
    int*       rs    = (int*)alloc((size_t)(N_NODES + 1) * 4);
    int*       cur   = (int*)alloc((size_t)N_NODES * 4);
    int*       elist = (int*)alloc((size_t)E2 * 4);
    unsigned*  g     = (unsigned*)alloc((size_t)G_GRAPHS * H * 4);
    float*     g1    = (float*)alloc((size_t)G_GRAPHS * OUT_DIM * 4);

    k_zero<<<40, 256, 0, stream>>>(deg, cur, g);
    k_count<<<(E2 + 255) / 256, 256, 0, stream>>>(ei, deg);
    k_scan<<<1, 1024, 0, stream>>>(deg, rs);
    k_fill<<<(E2 + 255) / 256, 256, 0, stream>>>(ei, rs, cur, elist);
    k_vw<<<L_LAYERS, 512, 0, stream>>>(Wsrc, Wdst, att_src, att_dst, vsrc, vdst);
    k_mm<<<256, 256, 0, stream>>>(Wsrc, Wout, M);
    k_pack_out<<<4096, 256, 0, stream>>>(M, WpM);
    k_pack_win<<<128, 256, 0, stream>>>(W_in, WpI);
    k_in_mfma<<<N_NODES / 16, 256, 0, stream>>>(x, WpI, b_in, ln_in_w, ln_in_b, h, hb);

    for (int l = 0; l < L_LAYERS; l++) {
        k_alpha<<<N_NODES / 4, 256, 0, stream>>>(h, vsrc, vdst, as_, ad_, l);
        k_aggout<<<N_NODES / 16, 256, 0, stream>>>(hb, (const float4*)as_, (const float4*)ad_,
                                                   rs, elist, WpM, bout, ln_w, ln_b, h, hb, l);
    }

    k_pool<<<100, 128, 0, stream>>>(h, batch, g);
    k_mlp1<<<G_GRAPHS * 4, 256, 0, stream>>>(g, Wp1, bp1, g1);
    k_mlp2<<<G_GRAPHS * 16, 256, 0, stream>>>(g1, Wp2, bp2, (float*)d_out);
}

// Round 8
// 707.953 us; speedup vs baseline: 3.0562x; 1.0167x over previous
//
#include <hip/hip_runtime.h>
#include <hip/hip_bf16.h>

#define N_NODES 10000
#define E_EDGES 160000
#define E2 (E_EDGES + N_NODES)
#define D_IN 256
#define H 128
#define HEADS 4
#define HD 512
#define L_LAYERS 16
#define OUT_DIM 1024
#define G_GRAPHS 8
#define EPS 1e-5f
#define SPAD 10016

typedef unsigned short ushort_t;
typedef __attribute__((ext_vector_type(8))) short short8;
typedef __attribute__((ext_vector_type(4))) float f32x4;
typedef __attribute__((ext_vector_type(4))) unsigned u32x4;

__device__ __forceinline__ f32x4 mfma16(short8 a, short8 b, f32x4 c) {
    return __builtin_amdgcn_mfma_f32_16x16x32_bf16(a, b, c, 0, 0, 0);
}
__device__ __forceinline__ unsigned short f2b(float f) {   // f32 -> bf16 bits, RNE
    unsigned u = __float_as_uint(f);
    u += 0x7fffu + ((u >> 16) & 1u);
    return (unsigned short)(u >> 16);
}
__device__ __forceinline__ float b2f(unsigned short b) {
    return __uint_as_float((unsigned)b << 16);
}
__device__ __forceinline__ unsigned pk2(float lo, float hi) {  // 2xf32 -> packed bf16x2
    __hip_bfloat162 p = __float22bfloat162_rn(make_float2(lo, hi));
    return *(unsigned*)&p;
}

// ---------------- setup: CSR build (int32 edges) ----------------
__global__ void k_zero(int* deg, int* cur, unsigned* g) {
    int i = blockIdx.x * blockDim.x + threadIdx.x;
    if (i < N_NODES) { deg[i] = 0; cur[i] = 0; }
    if (i < G_GRAPHS * H) g[i] = 0u;
}

__global__ void k_count(const int* ei, int* deg) {
    int e = blockIdx.x * blockDim.x + threadIdx.x;
    if (e >= E2) return;
    int d = (e < E_EDGES) ? ei[E_EDGES + e] : (e - E_EDGES);
    atomicAdd(&deg[d], 1);
}

__global__ void k_scan(const int* deg, int* rs) {   // 1 block x 1024, 10 elems/thread
    __shared__ int s[1024];
    int t = threadIdx.x;
    int base = t * 10;
    int loc[10], run = 0;
    #pragma unroll
    for (int i = 0; i < 10; i++) {
        int idx = base + i;
        int v = (idx < N_NODES) ? deg[idx] : 0;
        loc[i] = run; run += v;
    }
    s[t] = run;
    __syncthreads();
    for (int off = 1; off < 1024; off <<= 1) {
        int xv = (t >= off) ? s[t - off] : 0;
        __syncthreads();
        s[t] += xv;
        __syncthreads();
    }
    int excl = s[t] - run;
    #pragma unroll
    for (int i = 0; i < 10; i++) {
        int idx = base + i;
        if (idx <= N_NODES) rs[idx] = excl + loc[i];
    }
}

__global__ void k_fill(const int* ei, const int* rs, int* cur, int* elist) {
    int e = blockIdx.x * blockDim.x + threadIdx.x;
    if (e >= E2) return;
    int s, d;
    if (e < E_EDGES) { s = ei[e]; d = ei[E_EDGES + e]; }
    else { s = d = e - E_EDGES; }
    int pos = atomicAdd(&cur[d], 1);
    elist[rs[d] + pos] = s;
}

// ---------------- weight preprocessing ----------------
// vsrc[l][head*H + j] = sum_k Wsrc[l][j][head*H+k] * att_src[l][head][k]
__global__ void k_vw(const float* Wsrc, const float* Wdst,
                     const float* att_src, const float* att_dst,
                     float* vsrc, float* vdst) {
    int l = blockIdx.x;
    int t = threadIdx.x;           // 512
    int head = t >> 7, j = t & 127;
    const float* Ws = Wsrc + (size_t)l * H * HD;
    const float* Wd = Wdst + (size_t)l * H * HD;
    const float* As = att_src + (size_t)l * HEADS * H;
    const float* Ad = att_dst + (size_t)l * HEADS * H;
    float ss = 0.f, sd = 0.f;
    for (int k = 0; k < H; k++) {
        ss += Ws[(size_t)j * HD + head * H + k] * As[head * H + k];
        sd += Wd[(size_t)j * HD + head * H + k] * Ad[head * H + k];
    }
    vsrc[(size_t)l * HD + head * H + j] = ss;
    vdst[(size_t)l * HD + head * H + j] = sd;
}

// M[l][h*128+k][o] = sum_c Wsrc[l][k][h*128+c] * Wout[l][h*128+c][o]
// tiled: 256 blocks = (l,h,quarter); 256 thr; thread computes 2x8; K tiles of 32
__global__ __launch_bounds__(256) void k_mm(const float* __restrict__ Wsrc,
        const float* __restrict__ Wout, float* __restrict__ M) {
    __shared__ float As[32][33];
    __shared__ float Bs[32][128];
    int bid = blockIdx.x;
    int q = bid & 3, hh = (bid >> 2) & 3, l = bid >> 4;
    int t = threadIdx.x;
    int ty = t >> 4, tx = t & 15;
    const float* WsB = Wsrc + (size_t)l * H * HD + (size_t)hh * 128;
    const float* WoB = Wout + (size_t)l * HD * H + (size_t)hh * 128 * H;
    float acc[2][8];
    #pragma unroll
    for (int r = 0; r < 2; r++)
        #pragma unroll
        for (int c = 0; c < 8; c++) acc[r][c] = 0.f;
    for (int kt = 0; kt < 4; kt++) {
        #pragma unroll
        for (int i = 0; i < 4; i++) {
            int lin = i * 256 + t;
            int rr = lin >> 5, cc = lin & 31;
            As[rr][cc] = WsB[(size_t)(q * 32 + rr) * HD + kt * 32 + cc];
        }
        #pragma unroll
        for (int i = 0; i < 16; i++) {
            int lin = i * 256 + t;
            int rr = lin >> 7, cc = lin & 127;
            Bs[rr][cc] = WoB[(size_t)(kt * 32 + rr) * H + cc];
        }
        __syncthreads();
        #pragma unroll
        for (int kk = 0; kk < 32; kk++) {
            float a0 = As[ty * 2][kk], a1 = As[ty * 2 + 1][kk];
            float4 b0 = *(const float4*)&Bs[kk][tx * 8];
            float4 b1 = *(const float4*)&Bs[kk][tx * 8 + 4];
            acc[0][0] += a0 * b0.x; acc[0][1] += a0 * b0.y;
            acc[0][2] += a0 * b0.z; acc[0][3] += a0 * b0.w;
            acc[0][4] += a0 * b1.x; acc[0][5] += a0 * b1.y;
            acc[0][6] += a0 * b1.z; acc[0][7] += a0 * b1.w;
            acc[1][0] += a1 * b0.x; acc[1][1] += a1 * b0.y;
            acc[1][2] += a1 * b0.z; acc[1][3] += a1 * b0.w;
            acc[1][4] += a1 * b1.x; acc[1][5] += a1 * b1.y;
            acc[1][6] += a1 * b1.z; acc[1][7] += a1 * b1.w;
        }
        __syncthreads();
    }
    #pragma unroll
    for (int r = 0; r < 2; r++)
        #pragma unroll
        for (int c = 0; c < 8; c++)
            M[(size_t)l * HD * H + (size_t)(hh * 128 + q * 32 + ty * 2 + r) * H + tx * 8 + c]
                = acc[r][c];
}

// pack M [L][512k][128col] f32 -> hi/lo B-frag layout [L][nt8][ks16][lane64][j8] bf16
__global__ void k_pack_out2(const float* M, ushort_t* Wh, ushort_t* Wl) {
    int idx = blockIdx.x * 256 + threadIdx.x;           // 16*65536 total
    int l = idx >> 16, rem = idx & 65535;
    int k = rem >> 7, col = rem & 127;
    float v = M[(size_t)l * HD * H + (size_t)k * H + col];
    unsigned short hi = f2b(v);
    unsigned short lo = f2b(v - b2f(hi));
    int nt = col >> 4, ks = k >> 5, lhi = (k >> 3) & 3, llo = col & 15, j = k & 7;
    size_t addr = (size_t)l * 65536 + (((size_t)(nt * 16 + ks) * 64) + lhi * 16 + llo) * 8 + j;
    Wh[addr] = hi;
    Wl[addr] = lo;
}

// pack W_in [256k][128col] f32 -> [nt8][ks8][lane64][j8] bf16
__global__ void k_pack_win(const float* W, ushort_t* Wp) {
    int idx = blockIdx.x * 256 + threadIdx.x;           // 32768 total
    int k = idx >> 7, col = idx & 127;
    float v = W[(size_t)k * H + col];
    int nt = col >> 4, ks = k >> 5, lhi = (k >> 3) & 3, llo = col & 15, j = k & 7;
    Wp[(((size_t)(nt * 8 + ks) * 64) + lhi * 16 + llo) * 8 + j] = f2b(v);
}

// ---------------- input layer: MFMA + LN + relu + layer-0 alpha epilogue ----------------
__global__ __launch_bounds__(256) void k_in_mfma(
        const float* __restrict__ x, const ushort_t* __restrict__ WpI,
        const float* __restrict__ b_in, const float* __restrict__ lnw,
        const float* __restrict__ lnb, const float* __restrict__ vs,
        const float* __restrict__ vd, float* __restrict__ as0, float* __restrict__ ad0,
        float* __restrict__ h, ushort_t* __restrict__ hb) {
    __shared__ float part1[4][16], part2[4][16];
    __shared__ float apart[4][8][16];
    int t = threadIdx.x, w = t >> 6, lane = t & 63;
    int row0 = blockIdx.x * 16;
    int ar = lane & 15, ac = (lane >> 4) * 8;
    short8 a[8];
    #pragma unroll
    for (int ks = 0; ks < 8; ks++) {
        const float* xp = x + (size_t)(row0 + ar) * D_IN + ks * 32 + ac;
        float4 xa = *(const float4*)xp;
        float4 xb = *(const float4*)(xp + 4);
        u32x4 u;
        u.x = pk2(xa.x, xa.y); u.y = pk2(xa.z, xa.w);
        u.z = pk2(xb.x, xb.y); u.w = pk2(xb.z, xb.w);
        a[ks] = *(short8*)&u;
    }
    const ushort_t* B0 = WpI + ((size_t)(w * 2 + 0) * 8) * 64 * 8;
    const ushort_t* B1 = WpI + ((size_t)(w * 2 + 1) * 8) * 64 * 8;
    f32x4 c0 = {0.f, 0.f, 0.f, 0.f}, c1 = {0.f, 0.f, 0.f, 0.f};
    #pragma unroll
    for (int ks = 0; ks < 8; ks++) {
        short8 b0 = *(const short8*)(B0 + ((size_t)ks * 64 + lane) * 8);
        short8 b1 = *(const short8*)(B1 + ((size_t)ks * 64 + lane) * 8);
        c0 = mfma16(a[ks], b0, c0);
        c1 = mfma16(a[ks], b1, c1);
    }
    int col0 = w * 32 + ar, col1 = w * 32 + 16 + ar;
    int rb = (lane >> 4) * 4;
    float v0[4], v1[4], y0[4], y1[4];
    #pragma unroll
    for (int r = 0; r < 4; r++) {
        v0[r] = c0[r] + b_in[col0];
        v1[r] = c1[r] + b_in[col1];
        float p1 = v0[r] + v1[r];
        float p2 = v0[r] * v0[r] + v1[r] * v1[r];
        #pragma unroll
        for (int off = 1; off < 16; off <<= 1) {
            p1 += __shfl_xor(p1, off);
            p2 += __shfl_xor(p2, off);
        }
        if (ar == 0) { part1[w][rb + r] = p1; part2[w][rb + r] = p2; }
    }
    __syncthreads();
    #pragma unroll
    for (int r = 0; r < 4; r++) {
        int lr = rb + r;
        int row = row0 + lr;
        float s1 = part1[0][lr] + part1[1][lr] + part1[2][lr] + part1[3][lr];
        float s2 = part2[0][lr] + part2[1][lr] + part2[2][lr] + part2[3][lr];
        float m = s1 * (1.f / 128.f);
        float var = s2 * (1.f / 128.f) - m * m;
        float is = rsqrtf(var + EPS);
        y0[r] = fmaxf((v0[r] - m) * is * lnw[col0] + lnb[col0], 0.f);
        y1[r] = fmaxf((v1[r] - m) * is * lnw[col1] + lnb[col1], 0.f);
        h[(size_t)row * H + col0] = y0[r];
        h[(size_t)row * H + col1] = y1[r];
        hb[(size_t)row * H + col0] = f2b(y0[r]);
        hb[(size_t)row * H + col1] = f2b(y1[r]);
    }
    // layer-0 alpha epilogue
    #pragma unroll
    for (int comp = 0; comp < 8; comp++) {
        float vc0 = (comp < 4) ? vs[comp * H + col0] : vd[(comp - 4) * H + col0];
        float vc1 = (comp < 4) ? vs[comp * H + col1] : vd[(comp - 4) * H + col1];
        float p[4];
        #pragma unroll
        for (int r = 0; r < 4; r++) p[r] = y0[r] * vc0 + y1[r] * vc1;
        #pragma unroll
        for (int off = 1; off < 16; off <<= 1)
            #pragma unroll
            for (int r = 0; r < 4; r++) p[r] += __shfl_xor(p[r], off);
        if (ar == 0)
            #pragma unroll
            for (int r = 0; r < 4; r++) apart[w][comp][rb + r] = p[r];
    }
    __syncthreads();
    if (t < 128) {
        int lr = t >> 3, comp = t & 7;
        float s = apart[0][comp][lr] + apart[1][comp][lr]
                + apart[2][comp][lr] + apart[3][comp][lr];
        int node = row0 + lr;
        if (comp < 4) as0[node * 4 + comp] = s;
        else          ad0[node * 4 + comp - 4] = s;
    }
}

// ---------------- fused T-agg + folded out-GEMM(hi+lo) + LN + next-layer alpha ----------------
// hb_in / hb_out are DISTINCT buffers (double-buffered across layers; no gather race)
#define ACC1(uv, wt) do { \
    acc[0] += (wt) * __uint_as_float((uv).x << 16); \
    acc[1] += (wt) * __uint_as_float((uv).x & 0xffff0000u); \
    acc[2] += (wt) * __uint_as_float((uv).y << 16); \
    acc[3] += (wt) * __uint_as_float((uv).y & 0xffff0000u); \
    acc[4] += (wt) * __uint_as_float((uv).z << 16); \
    acc[5] += (wt) * __uint_as_float((uv).z & 0xffff0000u); \
    acc[6] += (wt) * __uint_as_float((uv).w << 16); \
    acc[7] += (wt) * __uint_as_float((uv).w & 0xffff0000u); \
} while (0)

__global__ __launch_bounds__(512) void k_aggout(
        const ushort_t* __restrict__ hb, const float4* __restrict__ as4,
        const float4* __restrict__ ad4, const int* __restrict__ rs,
        const int* __restrict__ elist, const ushort_t* __restrict__ Wh,
        const ushort_t* __restrict__ Wl, const float* __restrict__ bout,
        const float* __restrict__ lnw, const float* __restrict__ lnb,
        const float* __restrict__ vsn, const float* __restrict__ vdn,
        float* __restrict__ asn, float* __restrict__ adn, int doAlpha,
        float* __restrict__ h, ushort_t* __restrict__ hbo, int l) {
    __shared__ ushort_t frag[16 * 64 * 8];      // 16KB
    __shared__ int sl[8][64];
    __shared__ float wl[8][64][4];
    __shared__ float part1[8][16], part2[8][16];
    __shared__ float apart[8][8][16];
    int t = threadIdx.x, w = t >> 6, lane = t & 63;
    int base = blockIdx.x * 16;
    int head = lane >> 4;
    int j8 = (lane & 15) * 8;

    // ---- phase 1: aggregate T for 2 nodes per wave ----
    for (int q = 0; q < 2; q++) {
        int r = w * 2 + q;
        int node = base + r;
        int start = rs[node], end = rs[node + 1];
        float4 adv = ad4[node];
        float acc[8];
        #pragma unroll
        for (int i = 0; i < 8; i++) acc[i] = 0.f;
        for (int c0 = start; c0 < end; c0 += 64) {
            int cnt = min(64, end - c0);
            if (lane < cnt) {
                int s = elist[c0 + lane];
                sl[w][lane] = s;
                float4 av = as4[s];
                float l0 = av.x + adv.x, l1 = av.y + adv.y, l2 = av.z + adv.z, l3 = av.w + adv.w;
                l0 = (l0 > 0.f) ? l0 : 0.2f * l0;
                l1 = (l1 > 0.f) ? l1 : 0.2f * l1;
                l2 = (l2 > 0.f) ? l2 : 0.2f * l2;
                l3 = (l3 > 0.f) ? l3 : 0.2f * l3;
                float mx = fmaxf(fmaxf(l0, l1), fmaxf(l2, l3));
                float e0 = expf(l0 - mx), e1 = expf(l1 - mx), e2 = expf(l2 - mx), e3 = expf(l3 - mx);
                float inv = 1.f / (e0 + e1 + e2 + e3);
                wl[w][lane][0] = e0 * inv;
                wl[w][lane][1] = e1 * inv;
                wl[w][lane][2] = e2 * inv;
                wl[w][lane][3] = e3 * inv;
            }
            __asm__ volatile("s_waitcnt lgkmcnt(0)" ::: "memory");
            int j = 0;
            if (cnt >= 4) {
                u32x4 b0, b1, b2, b3;
                float q0, q1, q2, q3;
                {
                    int s0 = sl[w][0], s1 = sl[w][1], s2 = sl[w][2], s3 = sl[w][3];
                    q0 = wl[w][0][head]; q1 = wl[w][1][head];
                    q2 = wl[w][2][head]; q3 = wl[w][3][head];
                    b0 = *(const u32x4*)(hb + (size_t)s0 * H + j8);
                    b1 = *(const u32x4*)(hb + (size_t)s1 * H + j8);
                    b2 = *(const u32x4*)(hb + (size_t)s2 * H + j8);
                    b3 = *(const u32x4*)(hb + (size_t)s3 * H + j8);
                }
                for (j = 4; j + 3 < cnt; j += 4) {
                    int s0 = sl[w][j], s1 = sl[w][j + 1], s2 = sl[w][j + 2], s3 = sl[w][j + 3];
                    u32x4 n0 = *(const u32x4*)(hb + (size_t)s0 * H + j8);
                    u32x4 n1 = *(const u32x4*)(hb + (size_t)s1 * H + j8);
                    u32x4 n2 = *(const u32x4*)(hb + (size_t)s2 * H + j8);
                    u32x4 n3 = *(const u32x4*)(hb + (size_t)s3 * H + j8);
                    float r0 = wl[w][j][head], r1 = wl[w][j + 1][head];
                    float r2 = wl[w][j + 2][head], r3 = wl[w][j + 3][head];
                    ACC1(b0, q0); ACC1(b1, q1); ACC1(b2, q2); ACC1(b3, q3);
                    b0 = n0; q0 = r0; b1 = n1; q1 = r1;
                    b2 = n2; q2 = r2; b3 = n3; q3 = r3;
                }
                ACC1(b0, q0); ACC1(b1, q1); ACC1(b2, q2); ACC1(b3, q3);
            }
            for (; j < cnt; j++) {
                int s = sl[w][j];
                float wt = wl[w][j][head];
                u32x4 uv = *(const u32x4*)(hb + (size_t)s * H + j8);
                ACC1(uv, wt);
            }
        }
        u32x4 o;
        o.x = pk2(acc[0], acc[1]);
        o.y = pk2(acc[2], acc[3]);
        o.z = pk2(acc[4], acc[5]);
        o.w = pk2(acc[6], acc[7]);
        int ksn = head * 4 + ((lane >> 2) & 3);
        int gidx = ((lane & 3) * 16 + r) * 16 + (ksn ^ r);
        *(u32x4*)((char*)frag + gidx * 16) = o;
    }
    __syncthreads();

    // ---- phase 2: out-GEMM 16x128, K=512, B = M_hi + M_lo ----
    const ushort_t* WLh = Wh + (size_t)l * 65536;
    const ushort_t* WLl = Wl + (size_t)l * 65536;
    short8 a[16];
    #pragma unroll
    for (int ks = 0; ks < 16; ks++) {
        int gidx = lane * 16 + (ks ^ (lane & 15));
        a[ks] = *(const short8*)((const char*)frag + gidx * 16);
    }
    int ar = lane & 15;
    f32x4 c = {0.f, 0.f, 0.f, 0.f};
    #pragma unroll
    for (int ks = 0; ks < 16; ks++) {
        short8 bh = *(const short8*)(WLh + ((size_t)(w * 16 + ks) * 64 + lane) * 8);
        c = mfma16(a[ks], bh, c);
    }
    #pragma unroll
    for (int ks = 0; ks < 16; ks++) {
        short8 bl = *(const short8*)(WLl + ((size_t)(w * 16 + ks) * 64 + lane) * 8);
        c = mfma16(a[ks], bl, c);
    }

    // ---- phase 3: bias + residual + LN + relu ----
    const float* bo = bout + (size_t)l * H;
    const float* gw = lnw + (size_t)l * H;
    const float* gb = lnb + (size_t)l * H;
    int col = w * 16 + ar;
    int rb = (lane >> 4) * 4;
    float v[4], y[4];
    #pragma unroll
    for (int r = 0; r < 4; r++) {
        int row = base + rb + r;
        v[r] = c[r] + bo[col] + h[(size_t)row * H + col];
        float p1 = v[r];
        float p2 = v[r] * v[r];
        #pragma unroll
        for (int off = 1; off < 16; off <<= 1) {
            p1 += __shfl_xor(p1, off);
            p2 += __shfl_xor(p2, off);
        }
        if (ar == 0) { part1[w][rb + r] = p1; part2[w][rb + r] = p2; }
    }
    __syncthreads();
    #pragma unroll
    for (int r = 0; r < 4; r++) {
        int lr = rb + r;
        int row = base + lr;
        float s1 = 0.f, s2 = 0.f;
        #pragma unroll
        for (int ww = 0; ww < 8; ww++) { s1 += part1[ww][lr]; s2 += part2[ww][lr]; }
        float m = s1 * (1.f / 128.f);
        float var = s2 * (1.f / 128.f) - m * m;
        float is = rsqrtf(var + EPS);
        y[r] = fmaxf((v[r] - m) * is * gw[col] + gb[col], 0.f);
        h[(size_t)row * H + col] = y[r];
        hbo[(size_t)row * H + col] = f2b(y[r]);
    }

    // ---- phase 4: next-layer alpha epilogue ----
    if (doAlpha) {
        #pragma unroll
        for (int comp = 0; comp < 8; comp++) {
            float vc = (comp < 4) ? vsn[comp * H + col] : vdn[(comp - 4) * H + col];
            float p[4];
            #pragma unroll
            for (int r = 0; r < 4; r++) p[r] = y[r] * vc;
            #pragma unroll
            for (int off = 1; off < 16; off <<= 1)
                #pragma unroll
                for (int r = 0; r < 4; r++) p[r] += __shfl_xor(p[r], off);
            if (ar == 0)
                #pragma unroll
                for (int r = 0; r < 4; r++) apart[w][comp][rb + r] = p[r];
        }
        __syncthreads();
        if (t < 128) {
            int lr = t >> 3, comp = t & 7;
            float s = 0.f;
            #pragma unroll
            for (int ww = 0; ww < 8; ww++) s += apart[ww][comp][lr];
            int node = base + lr;
            if (comp < 4) asn[node * 4 + comp] = s;
            else          adn[node * 4 + comp - 4] = s;
        }
    }
}

// ---------------- pooling + MLPs ----------------
__global__ void k_pool(const float* __restrict__ h, const int* __restrict__ batch,
                       unsigned* __restrict__ g) {
    __shared__ float lm[G_GRAPHS][H];
    int t = threadIdx.x;
    #pragma unroll
    for (int i = 0; i < G_GRAPHS; i++) lm[i][t] = 0.f;
    int n0 = blockIdx.x * 100, n1 = n0 + 100;
    for (int n = n0; n < n1; n++) {
        int b = batch[n];
        lm[b][t] = fmaxf(lm[b][t], h[(size_t)n * H + t]);
    }
    #pragma unroll
    for (int i = 0; i < G_GRAPHS; i++)
        atomicMax(&g[i * H + t], __float_as_uint(lm[i][t]));
}

__global__ void k_mlp1(const unsigned* __restrict__ g, const float* __restrict__ Wp1,
                       const float* __restrict__ bp1, float* __restrict__ g1) {
    __shared__ float gs[H];
    int gr = blockIdx.x >> 2, ch = blockIdx.x & 3;
    int t = threadIdx.x;                        // 256
    if (t < H) gs[t] = __uint_as_float(g[gr * H + t]);
    __syncthreads();
    int col = ch * 256 + t;
    float acc = 0.f;
    for (int k = 0; k < H; k++) acc += gs[k] * Wp1[(size_t)k * OUT_DIM + col];
    acc += bp1[col];
    g1[(size_t)gr * OUT_DIM + col] = fmaxf(acc, 0.f);
}

__global__ void k_mlp2(const float* __restrict__ g1, const float* __restrict__ Wp2,
                       const float* __restrict__ bp2, float* __restrict__ out) {
    __shared__ float gs[OUT_DIM];
    __shared__ float part[4][64];
    int gr = blockIdx.x >> 4, ch = blockIdx.x & 15;
    int t = threadIdx.x;                        // 256
    int ci = t & 63, si = t >> 6;
    for (int i = t; i < OUT_DIM; i += 256) gs[i] = g1[(size_t)gr * OUT_DIM + i];
    __syncthreads();
    int col = ch * 64 + ci;
    float acc = 0.f;
    for (int k = si * 256; k < si * 256 + 256; k++)
        acc += gs[k] * Wp2[(size_t)k * OUT_DIM + col];
    part[si][ci] = acc;
    __syncthreads();
    if (si == 0) {
        float r = part[0][ci] + part[1][ci] + part[2][ci] + part[3][ci] + bp2[col];
        out[(size_t)gr * OUT_DIM + col] = r;
    }
}

// ---------------- launch ----------------
extern "C" void kernel_launch(void* const* d_in, const int* in_sizes, int n_in,
                              void* d_out, int out_size, void* d_ws, size_t ws_size,
                              hipStream_t stream) {
    const float* x       = (const float*)d_in[0];
    const int*   ei      = (const int*)d_in[1];     // int32
    const int*   batch   = (const int*)d_in[2];     // int32
    const float* W_in    = (const float*)d_in[3];
    const float* b_in    = (const float*)d_in[4];
    const float* ln_in_w = (const float*)d_in[5];
    const float* ln_in_b = (const float*)d_in[6];
    const float* Wsrc    = (const float*)d_in[7];
    const float* Wdst    = (const float*)d_in[8];
    const float* att_src = (const float*)d_in[9];
    const float* att_dst = (const float*)d_in[10];
    const float* Wout    = (const float*)d_in[11];
    const float* bout    = (const float*)d_in[12];
    const float* ln_w    = (const float*)d_in[13];
    const float* ln_b    = (const float*)d_in[14];
    const float* Wp1     = (const float*)d_in[15];
    const float* bp1     = (const float*)d_in[16];
    const float* Wp2     = (const float*)d_in[17];
    const float* bp2     = (const float*)d_in[18];

    char* w = (char*)d_ws;
    auto alloc = [&](size_t bytes) { void* p = w; w += (bytes + 255) & ~(size_t)255; return p; };
    float*     h     = (float*)alloc((size_t)N_NODES * H * 4);
    ushort_t*  hb0   = (ushort_t*)alloc((size_t)SPAD * H * 2);
    ushort_t*  hb1   = (ushort_t*)alloc((size_t)SPAD * H * 2);
    float*     as0   = (float*)alloc((size_t)SPAD * HEADS * 4);
    float*     ad0   = (float*)alloc((size_t)SPAD * HEADS * 4);
    float*     as1   = (float*)alloc((size_t)SPAD * HEADS * 4);
    float*     ad1   = (float*)alloc((size_t)SPAD * HEADS * 4);
    float*     vsrc  = (float*)alloc((size_t)L_LAYERS * HD * 4);
    float*     vdst  = (float*)alloc((size_t)L_LAYERS * HD * 4);
    float*     M     = (float*)alloc((size_t)L_LAYERS * HD * H * 4);
    ushort_t*  WpH   = (ushort_t*)alloc((size_t)L_LAYERS * 65536 * 2);
    ushort_t*  WpL   = (ushort_t*)alloc((size_t)L_LAYERS * 65536 * 2);
    ushort_t*  WpI   = (ushort_t*)alloc((size_t)D_IN * H * 2);
    int*       deg   = (int*)alloc((size_t)N_NODES * 4);
    int*       rs    = (int*)alloc((size_t)(N_NODES + 1) * 4);
    int*       cur   = (int*)alloc((size_t)N_NODES * 4);
    int*       elist = (int*)alloc((size_t)E2 * 4);
    unsigned*  g     = (unsigned*)alloc((size_t)G_GRAPHS * H * 4);
    float*     g1    = (float*)alloc((size_t)G_GRAPHS * OUT_DIM * 4);

    k_zero<<<40, 256, 0, stream>>>(deg, cur, g);
    k_count<<<(E2 + 255) / 256, 256, 0, stream>>>(ei, deg);
    k_scan<<<1, 1024, 0, stream>>>(deg, rs);
    k_fill<<<(E2 + 255) / 256, 256, 0, stream>>>(ei, rs, cur, elist);
    k_vw<<<L_LAYERS, 512, 0, stream>>>(Wsrc, Wdst, att_src, att_dst, vsrc, vdst);
    k_mm<<<256, 256, 0, stream>>>(Wsrc, Wout, M);
    k_pack_out2<<<4096, 256, 0, stream>>>(M, WpH, WpL);
    k_pack_win<<<128, 256, 0, stream>>>(W_in, WpI);
    k_in_mfma<<<N_NODES / 16, 256, 0, stream>>>(x, WpI, b_in, ln_in_w, ln_in_b,
                                                vsrc, vdst, as0, ad0, h, hb0);

    for (int l = 0; l < L_LAYERS; l++) {
        const ushort_t* hbi = (l & 1) ? hb1 : hb0;
        ushort_t*       hbo = (l & 1) ? hb0 : hb1;
        const float* aA = (l & 1) ? as1 : as0;
        const float* dA = (l & 1) ? ad1 : ad0;
        float* aB = (l & 1) ? as0 : as1;
        float* dB = (l & 1) ? ad0 : ad1;
        int ln = (l + 1 < L_LAYERS) ? (l + 1) : (L_LAYERS - 1);
        k_aggout<<<N_NODES / 16, 512, 0, stream>>>(
            hbi, (const float4*)aA, (const float4*)dA, rs, elist, WpH, WpL,
            bout, ln_w, ln_b, vsrc + (size_t)ln * HD, vdst + (size_t)ln * HD,
            aB, dB, (l + 1 < L_LAYERS) ? 1 : 0, h, hbo, l);
    }

    k_pool<<<100, 128, 0, stream>>>(h, batch, g);
    k_mlp1<<<G_GRAPHS * 4, 256, 0, stream>>>(g, Wp1, bp1, g1);
    k_mlp2<<<G_GRAPHS * 16, 256, 0, stream>>>(g1, Wp2, bp2, (float*)d_out);
}